// Round 1
// baseline (1770.797 us; speedup 1.0000x reference)
//
#include <hip/hip_runtime.h>
#include <hip/hip_bf16.h>
#include <math.h>

#define B_ 2
#define S_ 4096
#define D_ 512
#define H_ 8
#define DK_ 64
#define WIN_ 50

// ---------------- K1: build sorted compact list of global (ctrl) columns ----
__global__ __launch_bounds__(1024) void build_glist(const int* __restrict__ opcode,
                                                    int* __restrict__ glist,
                                                    int* __restrict__ gcount) {
    __shared__ int cnts[1024];
    int t = threadIdx.x;
    int f[4]; int c = 0;
    for (int k = 0; k < 4; ++k) {
        int col = t * 4 + k;
        int flag = 0;
        for (int b = 0; b < B_; ++b) flag |= (opcode[b * S_ + col] == 0) ? 1 : 0;
        f[k] = flag; c += flag;
    }
    cnts[t] = c;
    __syncthreads();
    // inclusive scan (Hillis-Steele) over 1024 per-thread counts
    for (int off = 1; off < 1024; off <<= 1) {
        int v = cnts[t];
        int add = (t >= off) ? cnts[t - off] : 0;
        __syncthreads();
        cnts[t] = v + add;
        __syncthreads();
    }
    int base = cnts[t] - c;   // exclusive
    for (int k = 0; k < 4; ++k) {
        if (f[k]) glist[base++] = t * 4 + k;
    }
    if (t == 1023) gcount[0] = cnts[1023];
}

// ---------------- K2: C = X @ W^T + bias ------------------------------------
// X [M=B*S, K=512] row-major, W [N=512, K=512] row-major (torch Linear weight).
// mode 0: out[m*D + n]  (plain row-major, final projection)
// mode 1: out[((b*H+h)*S + s)*DK + dk]  (scatter to [B,H,S,DK] for q/k/v)
__global__ __launch_bounds__(256) void gemm_xwt(const float* __restrict__ X,
                                                const float* __restrict__ W,
                                                const float* __restrict__ bias,
                                                float* __restrict__ out,
                                                int mode) {
    __shared__ float Xs[64][17];
    __shared__ float Ws[64][17];
    const int K = D_;
    int t = threadIdx.x;
    int tx = t & 15, ty = t >> 4;
    int m0 = blockIdx.y * 64, n0 = blockIdx.x * 64;
    int lr = t >> 4;   // load row base (0..15)
    int lc = t & 15;   // load k within tile
    float acc[4][4] = {};
    for (int k0 = 0; k0 < K; k0 += 16) {
        for (int i = 0; i < 4; ++i) {
            int r = lr + 16 * i;
            Xs[r][lc] = X[(size_t)(m0 + r) * K + k0 + lc];
            Ws[r][lc] = W[(size_t)(n0 + r) * K + k0 + lc];
        }
        __syncthreads();
        for (int kk = 0; kk < 16; ++kk) {
            float a[4], bb[4];
            for (int i = 0; i < 4; ++i) a[i]  = Xs[ty * 4 + i][kk];
            for (int j = 0; j < 4; ++j) bb[j] = Ws[tx * 4 + j][kk];
            for (int i = 0; i < 4; ++i)
                for (int j = 0; j < 4; ++j)
                    acc[i][j] += a[i] * bb[j];
        }
        __syncthreads();
    }
    for (int i = 0; i < 4; ++i) {
        int m = m0 + ty * 4 + i;
        for (int j = 0; j < 4; ++j) {
            int n = n0 + tx * 4 + j;
            float v = acc[i][j] + bias[n];
            if (mode == 0) {
                out[(size_t)m * D_ + n] = v;
            } else {
                int b = m >> 12, s = m & (S_ - 1);
                int h = n >> 6, dk = n & 63;
                out[(((size_t)(b * H_ + h) * S_) + s) * DK_ + dk] = v;
            }
        }
    }
}

// ---------------- K3: sparse flash attention --------------------------------
// Q,K,V in [B,H,S,DK] f32. AO out in [B,S,D] f32 (d = h*DK + dk).
__global__ __launch_bounds__(256) void attn_sparse(const float* __restrict__ Qp,
                                                   const float* __restrict__ Kp,
                                                   const float* __restrict__ Vp,
                                                   const int* __restrict__ glist,
                                                   const int* __restrict__ gcount,
                                                   float* __restrict__ AO) {
    __shared__ float Qs[64][65];
    __shared__ float Ks[64][65];
    __shared__ float Vs[64][65];
    __shared__ float Ps[64][65];
    __shared__ float mrow[64], lrow[64], frow[64];
    __shared__ int   jcol[64];

    int i0 = blockIdx.x * 64;
    int h  = blockIdx.y;
    int b  = blockIdx.z;
    int t  = threadIdx.x;
    int tx = t & 15, ty = t >> 4;
    const size_t headoff = ((size_t)(b * H_ + h)) * S_ * DK_;

    // load Q tile, pre-scaled by 1/sqrt(DK) = 1/8 (exact power of two)
    for (int i = 0; i < 16; ++i) {
        int idx = t + 256 * i;           // 0..4095
        int r = idx >> 6, d = idx & 63;
        Qs[r][d] = Qp[headoff + (size_t)(i0 + r) * DK_ + d] * 0.125f;
    }
    if (t < 64) { mrow[t] = -1e30f; lrow[t] = 0.f; }
    float O[4][4] = {};
    __syncthreads();

    int jt_lo = (i0 - WIN_) < 0 ? 0 : ((i0 - WIN_) >> 6);
    int jt_hi = (i0 + 63 + WIN_) >= S_ ? (S_ >> 6) - 1 : ((i0 + 63 + WIN_) >> 6);
    int nband = jt_hi - jt_lo + 1;
    int G = gcount[0];
    int nglob = (G + 63) >> 6;
    int nchunk = nband + nglob;

    for (int ch = 0; ch < nchunk; ++ch) {
        bool isband = ch < nband;
        // column indices for this chunk
        if (t < 64) {
            int j;
            if (isband) {
                j = (jt_lo + ch) * 64 + t;
            } else {
                int gi = (ch - nband) * 64 + t;
                j = (gi < G) ? glist[gi] : -1;
            }
            jcol[t] = j;
        }
        __syncthreads();
        // gather K,V chunk
        for (int i = 0; i < 16; ++i) {
            int idx = t + 256 * i;
            int r = idx >> 6, d = idx & 63;
            int j = jcol[r];
            float kv = 0.f, vv = 0.f;
            if (j >= 0) {
                kv = Kp[headoff + (size_t)j * DK_ + d];
                vv = Vp[headoff + (size_t)j * DK_ + d];
            }
            Ks[r][d] = kv;
            Vs[r][d] = vv;
        }
        __syncthreads();
        // scores (64x64), masked
        for (int i = 0; i < 4; ++i) {
            int r = ty * 4 + i;
            int iq = i0 + r;
            for (int j2 = 0; j2 < 4; ++j2) {
                int c = tx * 4 + j2;
                float s = 0.f;
                for (int dk = 0; dk < 64; ++dk) s += Qs[r][dk] * Ks[c][dk];
                int j = jcol[c];
                int ad = iq - j; if (ad < 0) ad = -ad;
                bool allow = (j >= 0) && (isband ? (ad <= WIN_) : (ad > WIN_));
                Ps[r][c] = allow ? s : -1e30f;
            }
        }
        __syncthreads();
        // online softmax row update
        if (t < 64) {
            float mo = mrow[t], mn = mo;
            for (int c = 0; c < 64; ++c) mn = fmaxf(mn, Ps[t][c]);
            float fac = expf(mo - mn);   // (-1e30)-(-1e30)=0 -> 1; else underflows to 0 correctly
            float sum = 0.f;
            for (int c = 0; c < 64; ++c) {
                float s = Ps[t][c];
                float p = (s <= -1e29f) ? 0.f : expf(s - mn);
                Ps[t][c] = p;
                sum += p;
            }
            lrow[t] = lrow[t] * fac + sum;
            mrow[t] = mn;
            frow[t] = fac;
        }
        __syncthreads();
        // rescale O, accumulate PV
        float fr[4];
        for (int i = 0; i < 4; ++i) fr[i] = frow[ty * 4 + i];
        for (int i = 0; i < 4; ++i)
            for (int j = 0; j < 4; ++j)
                O[i][j] *= fr[i];
        for (int c = 0; c < 64; ++c) {
            float p[4], v[4];
            for (int i = 0; i < 4; ++i) p[i] = Ps[ty * 4 + i][c];
            for (int j = 0; j < 4; ++j) v[j] = Vs[c][tx * 4 + j];
            for (int i = 0; i < 4; ++i)
                for (int j = 0; j < 4; ++j)
                    O[i][j] += p[i] * v[j];
        }
        __syncthreads();
    }

    // epilogue: normalize and write AO[b, s, h*DK + d]
    for (int i = 0; i < 4; ++i) {
        int r = ty * 4 + i;
        float l = lrow[r];
        float inv = (l > 0.f) ? (1.f / l) : 0.f;
        for (int j = 0; j < 4; ++j) {
            int d = tx * 4 + j;
            AO[((size_t)b * S_ + (i0 + r)) * D_ + h * DK_ + d] = O[i][j] * inv;
        }
    }
}

// ---------------- launch ----------------------------------------------------
extern "C" void kernel_launch(void* const* d_in, const int* in_sizes, int n_in,
                              void* d_out, int out_size, void* d_ws, size_t ws_size,
                              hipStream_t stream) {
    const float* x      = (const float*)d_in[0];
    const int*   opcode = (const int*)d_in[1];
    const float* Wq = (const float*)d_in[2];
    const float* bq = (const float*)d_in[3];
    const float* Wk = (const float*)d_in[4];
    const float* bk = (const float*)d_in[5];
    const float* Wv = (const float*)d_in[6];
    const float* bv = (const float*)d_in[7];
    const float* Wo = (const float*)d_in[8];
    const float* bo = (const float*)d_in[9];
    float* out = (float*)d_out;

    char* ws = (char*)d_ws;
    const size_t qkv_bytes = (size_t)B_ * S_ * D_ * sizeof(float);  // 16 MiB
    float* q  = (float*)(ws);
    float* k  = (float*)(ws + qkv_bytes);
    float* v  = (float*)(ws + 2 * qkv_bytes);
    float* ao = (float*)(ws + 3 * qkv_bytes);
    int* glist  = (int*)(ws + 4 * qkv_bytes);
    int* gcount = (int*)(ws + 4 * qkv_bytes + S_ * sizeof(int));

    build_glist<<<1, 1024, 0, stream>>>(opcode, glist, gcount);

    dim3 ggrid(D_ / 64, (B_ * S_) / 64);
    gemm_xwt<<<ggrid, 256, 0, stream>>>(x, Wq, bq, q, 1);
    gemm_xwt<<<ggrid, 256, 0, stream>>>(x, Wk, bk, k, 1);
    gemm_xwt<<<ggrid, 256, 0, stream>>>(x, Wv, bv, v, 1);

    dim3 agrid(S_ / 64, H_, B_);
    attn_sparse<<<agrid, 256, 0, stream>>>(q, k, v, glist, gcount, ao);

    gemm_xwt<<<ggrid, 256, 0, stream>>>(ao, Wo, bo, out, 0);
}

// Round 2
// 574.365 us; speedup vs baseline: 3.0831x; 3.0831x over previous
//
#include <hip/hip_runtime.h>
#include <hip/hip_bf16.h>
#include <math.h>

#define B_ 2
#define S_ 4096
#define D_ 512
#define H_ 8
#define DK_ 64
#define WIN_ 50

typedef __attribute__((ext_vector_type(8))) short short8;   // 8 bf16 bit-patterns (4 VGPRs)
typedef __attribute__((ext_vector_type(4))) float f32x4;    // MFMA accumulator

__device__ __forceinline__ unsigned short f2bf(float f) {
    unsigned u = __builtin_bit_cast(unsigned, f);
    u += 0x7FFF + ((u >> 16) & 1);   // RNE
    return (unsigned short)(u >> 16);
}

// ---------------- K1: build sorted compact list of global (ctrl) columns ----
__global__ __launch_bounds__(1024) void build_glist(const int* __restrict__ opcode,
                                                    int* __restrict__ glist,
                                                    int* __restrict__ gcount) {
    __shared__ int cnts[1024];
    int t = threadIdx.x;
    int f[4]; int c = 0;
    for (int k = 0; k < 4; ++k) {
        int col = t * 4 + k;
        int flag = 0;
        for (int b = 0; b < B_; ++b) flag |= (opcode[b * S_ + col] == 0) ? 1 : 0;
        f[k] = flag; c += flag;
    }
    cnts[t] = c;
    __syncthreads();
    for (int off = 1; off < 1024; off <<= 1) {
        int v = cnts[t];
        int add = (t >= off) ? cnts[t - off] : 0;
        __syncthreads();
        cnts[t] = v + add;
        __syncthreads();
    }
    int base = cnts[t] - c;
    for (int k = 0; k < 4; ++k) {
        if (f[k]) glist[base++] = t * 4 + k;
    }
    if (t == 1023) gcount[0] = cnts[1023];
}

// ---------------- K2: C = X @ W^T + bias (fp32 vector GEMM) -----------------
// mode 0: fp32 out[m*D + n]
// mode 1: bf16 scatter out[((b*H+h)*S + s)*DK + dk] with post-bias scale
__global__ __launch_bounds__(256) void gemm_xwt(const float* __restrict__ X,
                                                const float* __restrict__ W,
                                                const float* __restrict__ bias,
                                                void* __restrict__ outp,
                                                int mode, float scale) {
    __shared__ float Xs[64][17];
    __shared__ float Ws[64][17];
    const int K = D_;
    int t = threadIdx.x;
    int tx = t & 15, ty = t >> 4;
    int m0 = blockIdx.y * 64, n0 = blockIdx.x * 64;
    int lr = t >> 4;
    int lc = t & 15;
    float acc[4][4] = {};
    for (int k0 = 0; k0 < K; k0 += 16) {
        for (int i = 0; i < 4; ++i) {
            int r = lr + 16 * i;
            Xs[r][lc] = X[(size_t)(m0 + r) * K + k0 + lc];
            Ws[r][lc] = W[(size_t)(n0 + r) * K + k0 + lc];
        }
        __syncthreads();
        for (int kk = 0; kk < 16; ++kk) {
            float a[4], bb[4];
            for (int i = 0; i < 4; ++i) a[i]  = Xs[ty * 4 + i][kk];
            for (int j = 0; j < 4; ++j) bb[j] = Ws[tx * 4 + j][kk];
            for (int i = 0; i < 4; ++i)
                for (int j = 0; j < 4; ++j)
                    acc[i][j] += a[i] * bb[j];
        }
        __syncthreads();
    }
    for (int i = 0; i < 4; ++i) {
        int m = m0 + ty * 4 + i;
        for (int j = 0; j < 4; ++j) {
            int n = n0 + tx * 4 + j;
            float v = (acc[i][j] + bias[n]) * scale;
            if (mode == 0) {
                ((float*)outp)[(size_t)m * D_ + n] = v;
            } else {
                int b = m >> 12, s = m & (S_ - 1);
                int h = n >> 6, dk = n & 63;
                ((unsigned short*)outp)[(((size_t)(b * H_ + h) * S_) + s) * DK_ + dk] = f2bf(v);
            }
        }
    }
}

// ---------------- K3: sparse flash attention, bf16 MFMA ---------------------
// q (pre-scaled by 0.125), k, v : bf16 bits [B,H,S,DK]. AO out fp32 [B,S,D].
__global__ __launch_bounds__(256) void attn_mfma(const unsigned short* __restrict__ Qp,
                                                 const unsigned short* __restrict__ Kp,
                                                 const unsigned short* __restrict__ Vp,
                                                 const int* __restrict__ glist,
                                                 const int* __restrict__ gcount,
                                                 float* __restrict__ AO) {
    // LDS: K chunk [64 cols][64 dk], V^T chunk [64 dk][64 cols], P per-wave [16][64]
    // all bf16 with XOR swizzle: byte ^= (row&7)<<4 on a 128B row pitch.
    __shared__ unsigned short Ks[64 * 64];
    __shared__ unsigned short Vt[64 * 64];
    __shared__ unsigned short Ps[4 * 16 * 64];

    const int t = threadIdx.x;
    const int lane = t & 63;
    const int wave = t >> 6;
    const int lrow = lane & 15;     // m/n index within 16x16 tile
    const int lkg  = lane >> 4;     // k-group 0..3
    const int i0 = blockIdx.x * 64;
    const int h  = blockIdx.y;
    const int b  = blockIdx.z;
    const size_t headoff = ((size_t)(b * H_ + h)) * S_ * DK_;

    // Q fragments (A-layout): row = i0 + wave*16 + lrow, k = lkg*8 + j (+32*kt)
    short8 qa[2];
    {
        const unsigned short* qrow = Qp + headoff + (size_t)(i0 + wave * 16 + lrow) * DK_;
        qa[0] = *(const short8*)(qrow + 8 * lkg);
        qa[1] = *(const short8*)(qrow + 32 + 8 * lkg);
    }

    f32x4 Oa[4];
    for (int n = 0; n < 4; ++n) Oa[n] = f32x4{0.f, 0.f, 0.f, 0.f};
    float m_st[4] = {-1e30f, -1e30f, -1e30f, -1e30f};
    float l_st[4] = {0.f, 0.f, 0.f, 0.f};

    int jlo = i0 - WIN_;
    int jt_lo = (jlo < 0) ? 0 : (jlo >> 6);
    int jhi = i0 + 63 + WIN_; if (jhi > S_ - 1) jhi = S_ - 1;
    int jt_hi = jhi >> 6;
    int nband = jt_hi - jt_lo + 1;
    const int G = gcount[0];
    int nglob = (G + 63) >> 6;
    int nchunk = nband + nglob;

    for (int ch = 0; ch < nchunk; ++ch) {
        const bool isband = ch < nband;
        const int cbase = isband ? (jt_lo + ch) * 64 : 0;
        const int gbase = (ch - nband) * 64;

        __syncthreads();   // previous chunk's LDS reads complete before restage

        // ---- stage K and V^T into LDS ----
        {
            int j  = t & 63;        // chunk-column index == LDS row of Ks
            int hh = t >> 6;        // dk quarter
            int jj;
            if (isband) jj = cbase + j;
            else { int gi = gbase + j; jj = (gi < G) ? glist[gi] : -1; }
            const unsigned short* kr = Kp + headoff + (size_t)(jj < 0 ? 0 : jj) * DK_;
            const unsigned short* vr = Vp + headoff + (size_t)(jj < 0 ? 0 : jj) * DK_;
            for (int c2 = 0; c2 < 2; ++c2) {
                int col = hh * 16 + c2 * 8;
                short8 kv, vv;
                if (jj >= 0) {
                    kv = *(const short8*)(kr + col);
                    vv = *(const short8*)(vr + col);
                } else {
                    for (int e = 0; e < 8; ++e) { kv[e] = 0; vv[e] = 0; }
                }
                int kb = (j * 128 + col * 2) ^ ((j & 7) << 4);
                *(short8*)((char*)Ks + kb) = kv;
                for (int e = 0; e < 8; ++e) {
                    int dk = col + e;
                    int vb = (dk * 128 + j * 2) ^ ((dk & 7) << 4);
                    *(unsigned short*)((char*)Vt + vb) = (unsigned short)vv[e];
                }
            }
        }
        __syncthreads();

        // ---- QK^T: S-tile 16x64 per wave ----
        f32x4 sc[4];
        for (int n = 0; n < 4; ++n) sc[n] = f32x4{0.f, 0.f, 0.f, 0.f};
        for (int n = 0; n < 4; ++n) {
            for (int kt = 0; kt < 2; ++kt) {
                int row = n * 16 + lrow;
                int kb = (row * 128 + lkg * 16 + kt * 64) ^ ((row & 7) << 4);
                short8 bk = *(const short8*)((char*)Ks + kb);
                sc[n] = __builtin_amdgcn_mfma_f32_16x16x32_bf16(qa[kt], bk, sc[n], 0, 0, 0);
            }
        }

        // ---- mask + wave-parallel online softmax ----
        float rmax[4] = {-1e30f, -1e30f, -1e30f, -1e30f};
        for (int n = 0; n < 4; ++n) {
            int c = n * 16 + lrow;
            int jj;
            if (isband) jj = cbase + c;
            else { int gi = gbase + c; jj = (gi < G) ? glist[gi] : -1; }
            for (int r = 0; r < 4; ++r) {
                int iq = i0 + wave * 16 + lkg * 4 + r;
                int ad = iq - jj; ad = ad < 0 ? -ad : ad;
                bool allow = (jj >= 0) && (isband ? (ad <= WIN_) : (ad > WIN_));
                float s = allow ? sc[n][r] : -1e30f;
                sc[n][r] = s;
                rmax[r] = fmaxf(rmax[r], s);
            }
        }
        for (int msk = 1; msk < 16; msk <<= 1)
            for (int r = 0; r < 4; ++r)
                rmax[r] = fmaxf(rmax[r], __shfl_xor(rmax[r], msk, 64));

        float fac[4], rsum[4] = {0.f, 0.f, 0.f, 0.f};
        for (int r = 0; r < 4; ++r) {
            float mn = fmaxf(m_st[r], rmax[r]);
            fac[r] = __expf(m_st[r] - mn);
            m_st[r] = mn;
        }
        for (int n = 0; n < 4; ++n)
            for (int r = 0; r < 4; ++r) {
                float p = __expf(sc[n][r] - m_st[r]);
                sc[n][r] = p;
                rsum[r] += p;
            }
        for (int msk = 1; msk < 16; msk <<= 1)
            for (int r = 0; r < 4; ++r)
                rsum[r] += __shfl_xor(rsum[r], msk, 64);
        for (int r = 0; r < 4; ++r) l_st[r] = l_st[r] * fac[r] + rsum[r];

        // ---- P (D-layout) -> wave-private LDS (bf16, swizzled) ----
        unsigned short* Pw = Ps + wave * 16 * 64;
        for (int n = 0; n < 4; ++n)
            for (int r = 0; r < 4; ++r) {
                int row = lkg * 4 + r, col = n * 16 + lrow;
                int pb = (row * 128 + col * 2) ^ ((row & 7) << 4);
                *(unsigned short*)((char*)Pw + pb) = f2bf(sc[n][r]);
            }

        // ---- rescale O ----
        for (int n = 0; n < 4; ++n)
            for (int r = 0; r < 4; ++r) Oa[n][r] *= fac[r];

        // ---- PV: O += P @ V ----
        short8 pa[2];
        for (int kt = 0; kt < 2; ++kt) {
            int pb = (lrow * 128 + lkg * 16 + kt * 64) ^ ((lrow & 7) << 4);
            pa[kt] = *(const short8*)((char*)Pw + pb);
        }
        for (int n = 0; n < 4; ++n) {
            for (int kt = 0; kt < 2; ++kt) {
                int row = n * 16 + lrow;   // dk row of V^T
                int vb = (row * 128 + lkg * 16 + kt * 64) ^ ((row & 7) << 4);
                short8 bv = *(const short8*)((char*)Vt + vb);
                Oa[n] = __builtin_amdgcn_mfma_f32_16x16x32_bf16(pa[kt], bv, Oa[n], 0, 0, 0);
            }
        }
    }

    // ---- epilogue: normalize, write AO[b, s, h*64+dk] fp32 ----
    for (int r = 0; r < 4; ++r) {
        int iq = i0 + wave * 16 + lkg * 4 + r;
        float inv = 1.0f / l_st[r];
        for (int n = 0; n < 4; ++n) {
            int dk = n * 16 + lrow;
            AO[((size_t)b * S_ + iq) * D_ + h * DK_ + dk] = Oa[n][r] * inv;
        }
    }
}

// ---------------- launch ----------------------------------------------------
extern "C" void kernel_launch(void* const* d_in, const int* in_sizes, int n_in,
                              void* d_out, int out_size, void* d_ws, size_t ws_size,
                              hipStream_t stream) {
    const float* x      = (const float*)d_in[0];
    const int*   opcode = (const int*)d_in[1];
    const float* Wq = (const float*)d_in[2];
    const float* bq = (const float*)d_in[3];
    const float* Wk = (const float*)d_in[4];
    const float* bk = (const float*)d_in[5];
    const float* Wv = (const float*)d_in[6];
    const float* bv = (const float*)d_in[7];
    const float* Wo = (const float*)d_in[8];
    const float* bo = (const float*)d_in[9];
    float* out = (float*)d_out;

    char* ws = (char*)d_ws;
    const size_t bf_bytes  = (size_t)B_ * S_ * D_ * sizeof(unsigned short); // 8 MiB
    const size_t f32_bytes = (size_t)B_ * S_ * D_ * sizeof(float);          // 16 MiB
    unsigned short* qb = (unsigned short*)(ws);
    unsigned short* kb = (unsigned short*)(ws + bf_bytes);
    unsigned short* vb = (unsigned short*)(ws + 2 * bf_bytes);
    float* ao          = (float*)(ws + 3 * bf_bytes);
    int* glist  = (int*)(ws + 3 * bf_bytes + f32_bytes);
    int* gcount = (int*)(ws + 3 * bf_bytes + f32_bytes + S_ * sizeof(int));

    build_glist<<<1, 1024, 0, stream>>>(opcode, glist, gcount);

    dim3 ggrid(D_ / 64, (B_ * S_) / 64);
    gemm_xwt<<<ggrid, 256, 0, stream>>>(x, Wq, bq, qb, 1, 0.125f);
    gemm_xwt<<<ggrid, 256, 0, stream>>>(x, Wk, bk, kb, 1, 1.0f);
    gemm_xwt<<<ggrid, 256, 0, stream>>>(x, Wv, bv, vb, 1, 1.0f);

    dim3 agrid(S_ / 64, H_, B_);
    attn_mfma<<<agrid, 256, 0, stream>>>(qb, kb, vb, glist, gcount, ao);

    gemm_xwt<<<ggrid, 256, 0, stream>>>(ao, Wo, bo, out, 0, 1.0f);
}

// Round 3
// 311.858 us; speedup vs baseline: 5.6782x; 1.8417x over previous
//
#include <hip/hip_runtime.h>
#include <hip/hip_bf16.h>
#include <math.h>

#define B_ 2
#define S_ 4096
#define D_ 512
#define H_ 8
#define DK_ 64
#define WIN_ 50

typedef __attribute__((ext_vector_type(8))) short short8;   // 8 bf16 bit-patterns (4 VGPRs)
typedef __attribute__((ext_vector_type(4))) float f32x4;    // MFMA accumulator / float4
typedef __attribute__((ext_vector_type(4))) unsigned short us4;
typedef unsigned short ushort_t;

__device__ __forceinline__ unsigned short f2bf(float f) {
    unsigned u = __builtin_bit_cast(unsigned, f);
    u += 0x7FFF + ((u >> 16) & 1);   // RNE
    return (unsigned short)(u >> 16);
}
__device__ __forceinline__ float bf2f(unsigned short h) {
    return __builtin_bit_cast(float, ((unsigned)h) << 16);
}

// ---------------- K1: build sorted compact list of global (ctrl) columns ----
__global__ __launch_bounds__(1024) void build_glist(const int* __restrict__ opcode,
                                                    int* __restrict__ glist,
                                                    int* __restrict__ gcount) {
    __shared__ int cnts[1024];
    int t = threadIdx.x;
    int f[4]; int c = 0;
    for (int k = 0; k < 4; ++k) {
        int col = t * 4 + k;
        int flag = 0;
        for (int b = 0; b < B_; ++b) flag |= (opcode[b * S_ + col] == 0) ? 1 : 0;
        f[k] = flag; c += flag;
    }
    cnts[t] = c;
    __syncthreads();
    for (int off = 1; off < 1024; off <<= 1) {
        int v = cnts[t];
        int add = (t >= off) ? cnts[t - off] : 0;
        __syncthreads();
        cnts[t] = v + add;
        __syncthreads();
    }
    int base = cnts[t] - c;
    for (int k = 0; k < 4; ++k) {
        if (f[k]) glist[base++] = t * 4 + k;
    }
    if (t == 1023) gcount[0] = cnts[1023];
}

// ---------------- split kernels: fp32 -> bf16 hi + bf16 lo ------------------
__global__ __launch_bounds__(256) void split_x(const float* __restrict__ src,
                                               ushort_t* __restrict__ hi,
                                               ushort_t* __restrict__ lo) {
    int i = blockIdx.x * 256 + threadIdx.x;     // handles 4 floats
    f32x4 v = ((const f32x4*)src)[i];
    us4 h, l;
    for (int e = 0; e < 4; ++e) {
        unsigned short hb = f2bf(v[e]);
        h[e] = hb;
        l[e] = f2bf(v[e] - bf2f(hb));
    }
    ((us4*)hi)[i] = h;
    ((us4*)lo)[i] = l;
}

__global__ __launch_bounds__(256) void split_w4(const float* __restrict__ W0, const float* __restrict__ W1,
                                                const float* __restrict__ W2, const float* __restrict__ W3,
                                                ushort_t* __restrict__ H0, ushort_t* __restrict__ H1,
                                                ushort_t* __restrict__ H2, ushort_t* __restrict__ H3,
                                                ushort_t* __restrict__ L0, ushort_t* __restrict__ L1,
                                                ushort_t* __restrict__ L2, ushort_t* __restrict__ L3) {
    const float* src; ushort_t* hp; ushort_t* lp;
    switch (blockIdx.y) {
        case 0: src = W0; hp = H0; lp = L0; break;
        case 1: src = W1; hp = H1; lp = L1; break;
        case 2: src = W2; hp = H2; lp = L2; break;
        default: src = W3; hp = H3; lp = L3; break;
    }
    int i = blockIdx.x * 256 + threadIdx.x;
    f32x4 v = ((const f32x4*)src)[i];
    us4 h, l;
    for (int e = 0; e < 4; ++e) {
        unsigned short hb = f2bf(v[e]);
        h[e] = hb;
        l[e] = f2bf(v[e] - bf2f(hb));
    }
    ((us4*)hp)[i] = h;
    ((us4*)lp)[i] = l;
}

// ---------------- K2: MFMA GEMM, C = (Ah+Al) @ (Bh+Bl)^T + bias -------------
// A [8192, 512] as hi/lo bf16, B [512, 512] as hi/lo bf16 (torch W layout).
// mode 0: fp32 out[m*512 + n];  mode 1: bf16 scatter [B,H,S,DK], value*(scale).
// 128x128 tile, BK=32, 4 waves, double-buffered global_load_lds staging.
// LDS layout per buffer (ushort idx): tile(Ah0/Al1/Bh2/Bl3)*4096 + kg*1024 + row*8
__global__ __launch_bounds__(256) void gemm_mfma(const ushort_t* __restrict__ Ah,
                                                 const ushort_t* __restrict__ Al,
                                                 const ushort_t* __restrict__ Bh,
                                                 const ushort_t* __restrict__ Bl,
                                                 const float* __restrict__ bias,
                                                 void* __restrict__ outp,
                                                 int mode, float scale) {
    __shared__ ushort_t LDS[2][16384];   // 2 x 32 KB
    const int t = threadIdx.x;
    const int lane = t & 63, wave = t >> 6;
    const int lrow = lane & 15, lkg = lane >> 4;
    const int wr = wave >> 1, wc = wave & 1;
    const int m0 = blockIdx.y * 128, n0 = blockIdx.x * 128;

    const ushort_t* srcs[4] = {Ah, Al, Bh, Bl};
    const int row0[4] = {m0, m0, n0, n0};

    f32x4 acc[4][4];
    for (int m = 0; m < 4; ++m)
        for (int n = 0; n < 4; ++n)
            acc[m][n] = f32x4{0.f, 0.f, 0.f, 0.f};

    auto stage = [&](int buf, int k0) {
        #pragma unroll
        for (int it = 0; it < 8; ++it) {
            int c = it * 4 + wave;
            int tile = c >> 3;
            int kg = (c >> 1) & 3;
            int r = ((c & 1) << 6) | lane;
            const ushort_t* g = srcs[tile] + (size_t)(row0[tile] + r) * 512 + k0 + kg * 8;
            __builtin_amdgcn_global_load_lds(
                (const __attribute__((address_space(1))) void*)g,
                (__attribute__((address_space(3))) void*)(&LDS[buf][c * 512]),
                16, 0, 0);
        }
    };

    stage(0, 0);
    __syncthreads();

    const int aoff = lkg * 1024 + (wr * 64 + lrow) * 8;
    const int boff = 2 * 4096 + lkg * 1024 + (wc * 64 + lrow) * 8;
    int cur = 0;
    for (int ks = 0; ks < 16; ++ks) {
        if (ks < 15) stage(cur ^ 1, (ks + 1) * 32);
        const ushort_t* Lb = LDS[cur];
        short8 ah[4], al[4], bh[4], bl[4];
        #pragma unroll
        for (int m = 0; m < 4; ++m) {
            ah[m] = *(const short8*)(Lb + aoff + m * 128);
            al[m] = *(const short8*)(Lb + 4096 + aoff + m * 128);
        }
        #pragma unroll
        for (int n = 0; n < 4; ++n) {
            bh[n] = *(const short8*)(Lb + boff + n * 128);
            bl[n] = *(const short8*)(Lb + 4096 + boff + n * 128);
        }
        #pragma unroll
        for (int m = 0; m < 4; ++m)
            #pragma unroll
            for (int n = 0; n < 4; ++n) {
                acc[m][n] = __builtin_amdgcn_mfma_f32_16x16x32_bf16(ah[m], bh[n], acc[m][n], 0, 0, 0);
                acc[m][n] = __builtin_amdgcn_mfma_f32_16x16x32_bf16(al[m], bh[n], acc[m][n], 0, 0, 0);
                acc[m][n] = __builtin_amdgcn_mfma_f32_16x16x32_bf16(ah[m], bl[n], acc[m][n], 0, 0, 0);
            }
        __syncthreads();
        cur ^= 1;
    }

    // epilogue: D-layout row = A-idx (lkg*4+r), col = B-idx (lrow)
    for (int m = 0; m < 4; ++m)
        for (int n = 0; n < 4; ++n)
            for (int r = 0; r < 4; ++r) {
                int row = m0 + wr * 64 + m * 16 + lkg * 4 + r;
                int col = n0 + wc * 64 + n * 16 + lrow;
                float v = (acc[m][n][r] + bias[col]) * scale;
                if (mode == 0) {
                    ((float*)outp)[(size_t)row * D_ + col] = v;
                } else {
                    int b = row >> 12, s = row & (S_ - 1);
                    int h = col >> 6, dk = col & 63;
                    ((ushort_t*)outp)[(((size_t)(b * H_ + h) * S_) + s) * DK_ + dk] = f2bf(v);
                }
            }
}

// ---------------- K3: sparse flash attention, bf16 MFMA ---------------------
// q (pre-scaled by 0.125), k, v : bf16 bits [B,H,S,DK]. Out: ao hi/lo bf16 [B,S,D].
__global__ __launch_bounds__(256) void attn_mfma(const ushort_t* __restrict__ Qp,
                                                 const ushort_t* __restrict__ Kp,
                                                 const ushort_t* __restrict__ Vp,
                                                 const int* __restrict__ glist,
                                                 const int* __restrict__ gcount,
                                                 ushort_t* __restrict__ AOh,
                                                 ushort_t* __restrict__ AOl) {
    __shared__ ushort_t Ks[64 * 64];
    __shared__ ushort_t Vt[64 * 64];
    __shared__ ushort_t Ps[4 * 16 * 64];

    const int t = threadIdx.x;
    const int lane = t & 63;
    const int wave = t >> 6;
    const int lrow = lane & 15;
    const int lkg  = lane >> 4;
    const int i0 = blockIdx.x * 64;
    const int h  = blockIdx.y;
    const int b  = blockIdx.z;
    const size_t headoff = ((size_t)(b * H_ + h)) * S_ * DK_;

    short8 qa[2];
    {
        const ushort_t* qrow = Qp + headoff + (size_t)(i0 + wave * 16 + lrow) * DK_;
        qa[0] = *(const short8*)(qrow + 8 * lkg);
        qa[1] = *(const short8*)(qrow + 32 + 8 * lkg);
    }

    f32x4 Oa[4];
    for (int n = 0; n < 4; ++n) Oa[n] = f32x4{0.f, 0.f, 0.f, 0.f};
    float m_st[4] = {-1e30f, -1e30f, -1e30f, -1e30f};
    float l_st[4] = {0.f, 0.f, 0.f, 0.f};

    int jlo = i0 - WIN_;
    int jt_lo = (jlo < 0) ? 0 : (jlo >> 6);
    int jhi = i0 + 63 + WIN_; if (jhi > S_ - 1) jhi = S_ - 1;
    int jt_hi = jhi >> 6;
    int nband = jt_hi - jt_lo + 1;
    const int G = gcount[0];
    int nglob = (G + 63) >> 6;
    int nchunk = nband + nglob;

    for (int ch = 0; ch < nchunk; ++ch) {
        const bool isband = ch < nband;
        const int cbase = isband ? (jt_lo + ch) * 64 : 0;
        const int gbase = (ch - nband) * 64;

        __syncthreads();

        {
            int j  = t & 63;
            int hh = t >> 6;
            int jj;
            if (isband) jj = cbase + j;
            else { int gi = gbase + j; jj = (gi < G) ? glist[gi] : -1; }
            const ushort_t* kr = Kp + headoff + (size_t)(jj < 0 ? 0 : jj) * DK_;
            const ushort_t* vr = Vp + headoff + (size_t)(jj < 0 ? 0 : jj) * DK_;
            for (int c2 = 0; c2 < 2; ++c2) {
                int col = hh * 16 + c2 * 8;
                short8 kv, vv;
                if (jj >= 0) {
                    kv = *(const short8*)(kr + col);
                    vv = *(const short8*)(vr + col);
                } else {
                    for (int e = 0; e < 8; ++e) { kv[e] = 0; vv[e] = 0; }
                }
                int kb = (j * 128 + col * 2) ^ ((j & 7) << 4);
                *(short8*)((char*)Ks + kb) = kv;
                for (int e = 0; e < 8; ++e) {
                    int dk = col + e;
                    int vb = (dk * 128 + j * 2) ^ ((dk & 7) << 4);
                    *(ushort_t*)((char*)Vt + vb) = (ushort_t)vv[e];
                }
            }
        }
        __syncthreads();

        f32x4 sc[4];
        for (int n = 0; n < 4; ++n) sc[n] = f32x4{0.f, 0.f, 0.f, 0.f};
        for (int n = 0; n < 4; ++n) {
            for (int kt = 0; kt < 2; ++kt) {
                int row = n * 16 + lrow;
                int kb = (row * 128 + lkg * 16 + kt * 64) ^ ((row & 7) << 4);
                short8 bk = *(const short8*)((char*)Ks + kb);
                sc[n] = __builtin_amdgcn_mfma_f32_16x16x32_bf16(qa[kt], bk, sc[n], 0, 0, 0);
            }
        }

        float rmax[4] = {-1e30f, -1e30f, -1e30f, -1e30f};
        for (int n = 0; n < 4; ++n) {
            int c = n * 16 + lrow;
            int jj;
            if (isband) jj = cbase + c;
            else { int gi = gbase + c; jj = (gi < G) ? glist[gi] : -1; }
            for (int r = 0; r < 4; ++r) {
                int iq = i0 + wave * 16 + lkg * 4 + r;
                int ad = iq - jj; ad = ad < 0 ? -ad : ad;
                bool allow = (jj >= 0) && (isband ? (ad <= WIN_) : (ad > WIN_));
                float s = allow ? sc[n][r] : -1e30f;
                sc[n][r] = s;
                rmax[r] = fmaxf(rmax[r], s);
            }
        }
        for (int msk = 1; msk < 16; msk <<= 1)
            for (int r = 0; r < 4; ++r)
                rmax[r] = fmaxf(rmax[r], __shfl_xor(rmax[r], msk, 64));

        float fac[4], rsum[4] = {0.f, 0.f, 0.f, 0.f};
        for (int r = 0; r < 4; ++r) {
            float mn = fmaxf(m_st[r], rmax[r]);
            fac[r] = __expf(m_st[r] - mn);
            m_st[r] = mn;
        }
        for (int n = 0; n < 4; ++n)
            for (int r = 0; r < 4; ++r) {
                float p = __expf(sc[n][r] - m_st[r]);
                sc[n][r] = p;
                rsum[r] += p;
            }
        for (int msk = 1; msk < 16; msk <<= 1)
            for (int r = 0; r < 4; ++r)
                rsum[r] += __shfl_xor(rsum[r], msk, 64);
        for (int r = 0; r < 4; ++r) l_st[r] = l_st[r] * fac[r] + rsum[r];

        ushort_t* Pw = Ps + wave * 16 * 64;
        for (int n = 0; n < 4; ++n)
            for (int r = 0; r < 4; ++r) {
                int row = lkg * 4 + r, col = n * 16 + lrow;
                int pb = (row * 128 + col * 2) ^ ((row & 7) << 4);
                *(ushort_t*)((char*)Pw + pb) = f2bf(sc[n][r]);
            }

        for (int n = 0; n < 4; ++n)
            for (int r = 0; r < 4; ++r) Oa[n][r] *= fac[r];

        short8 pa[2];
        for (int kt = 0; kt < 2; ++kt) {
            int pb = (lrow * 128 + lkg * 16 + kt * 64) ^ ((lrow & 7) << 4);
            pa[kt] = *(const short8*)((char*)Pw + pb);
        }
        for (int n = 0; n < 4; ++n) {
            for (int kt = 0; kt < 2; ++kt) {
                int row = n * 16 + lrow;
                int vb = (row * 128 + lkg * 16 + kt * 64) ^ ((row & 7) << 4);
                short8 bv = *(const short8*)((char*)Vt + vb);
                Oa[n] = __builtin_amdgcn_mfma_f32_16x16x32_bf16(pa[kt], bv, Oa[n], 0, 0, 0);
            }
        }
    }

    for (int r = 0; r < 4; ++r) {
        int iq = i0 + wave * 16 + lkg * 4 + r;
        float inv = 1.0f / l_st[r];
        for (int n = 0; n < 4; ++n) {
            int dk = n * 16 + lrow;
            float v = Oa[n][r] * inv;
            unsigned short hb = f2bf(v);
            size_t idx = ((size_t)b * S_ + iq) * D_ + h * DK_ + dk;
            AOh[idx] = hb;
            AOl[idx] = f2bf(v - bf2f(hb));
        }
    }
}

// ---------------- launch ----------------------------------------------------
extern "C" void kernel_launch(void* const* d_in, const int* in_sizes, int n_in,
                              void* d_out, int out_size, void* d_ws, size_t ws_size,
                              hipStream_t stream) {
    const float* x      = (const float*)d_in[0];
    const int*   opcode = (const int*)d_in[1];
    const float* Wq = (const float*)d_in[2];
    const float* bq = (const float*)d_in[3];
    const float* Wk = (const float*)d_in[4];
    const float* bk = (const float*)d_in[5];
    const float* Wv = (const float*)d_in[6];
    const float* bv = (const float*)d_in[7];
    const float* Wo = (const float*)d_in[8];
    const float* bo = (const float*)d_in[9];
    float* out = (float*)d_out;

    char* ws = (char*)d_ws;
    const size_t bsd = (size_t)B_ * S_ * D_;              // 4.19M elems
    const size_t bf_bytes = bsd * sizeof(ushort_t);       // 8.39 MB
    const size_t w_bytes  = (size_t)D_ * D_ * sizeof(ushort_t); // 0.52 MB

    ushort_t* qb = (ushort_t*)(ws);
    ushort_t* kb = (ushort_t*)(ws + bf_bytes);
    ushort_t* vb = (ushort_t*)(ws + 2 * bf_bytes);
    ushort_t* xh = (ushort_t*)(ws + 3 * bf_bytes);
    ushort_t* xl = (ushort_t*)(ws + 4 * bf_bytes);
    // ao hi/lo reuse xh/xl after projections are done
    ushort_t* aoh = xh;
    ushort_t* aol = xl;
    char* wbase = ws + 5 * bf_bytes;
    ushort_t* Wh[4]; ushort_t* Wl[4];
    for (int i = 0; i < 4; ++i) {
        Wh[i] = (ushort_t*)(wbase + i * w_bytes);
        Wl[i] = (ushort_t*)(wbase + (4 + i) * w_bytes);
    }
    int* glist  = (int*)(wbase + 8 * w_bytes);
    int* gcount = (int*)(wbase + 8 * w_bytes + S_ * sizeof(int));

    build_glist<<<1, 1024, 0, stream>>>(opcode, glist, gcount);
    split_x<<<(int)(bsd / 4 / 256), 256, 0, stream>>>(x, xh, xl);
    split_w4<<<dim3(D_ * D_ / 4 / 256, 4), 256, 0, stream>>>(Wq, Wk, Wv, Wo,
        Wh[0], Wh[1], Wh[2], Wh[3], Wl[0], Wl[1], Wl[2], Wl[3]);

    dim3 ggrid(D_ / 128, (B_ * S_) / 128);
    gemm_mfma<<<ggrid, 256, 0, stream>>>(xh, xl, Wh[0], Wl[0], bq, qb, 1, 0.125f);
    gemm_mfma<<<ggrid, 256, 0, stream>>>(xh, xl, Wh[1], Wl[1], bk, kb, 1, 1.0f);
    gemm_mfma<<<ggrid, 256, 0, stream>>>(xh, xl, Wh[2], Wl[2], bv, vb, 1, 1.0f);

    dim3 agrid(S_ / 64, H_, B_);
    attn_mfma<<<agrid, 256, 0, stream>>>(qb, kb, vb, glist, gcount, aoh, aol);

    gemm_mfma<<<ggrid, 256, 0, stream>>>(aoh, aol, Wh[3], Wl[3], bo, out, 0, 1.0f);
}

// Round 4
// 258.469 us; speedup vs baseline: 6.8511x; 1.2066x over previous
//
#include <hip/hip_runtime.h>
#include <hip/hip_bf16.h>
#include <math.h>

#define B_ 2
#define S_ 4096
#define D_ 512
#define H_ 8
#define DK_ 64
#define WIN_ 50
#define NGT 32   // max global chunks (2048 cols; E[G]~780, 50 sigma margin)

typedef __attribute__((ext_vector_type(8))) short short8;   // 8 bf16 bit-patterns
typedef __attribute__((ext_vector_type(4))) float f32x4;
typedef __attribute__((ext_vector_type(4))) unsigned short us4;
typedef unsigned short ushort_t;

__device__ __forceinline__ unsigned short f2bf(float f) {
    unsigned u = __builtin_bit_cast(unsigned, f);
    u += 0x7FFF + ((u >> 16) & 1);   // RNE
    return (unsigned short)(u >> 16);
}
__device__ __forceinline__ float bf2f(unsigned short h) {
    return __builtin_bit_cast(float, ((unsigned)h) << 16);
}

// ---------------- K1: build sorted compact list of global (ctrl) columns ----
__global__ __launch_bounds__(1024) void build_glist(const int* __restrict__ opcode,
                                                    int* __restrict__ glist,
                                                    int* __restrict__ gcount) {
    __shared__ int cnts[1024];
    int t = threadIdx.x;
    int f[4]; int c = 0;
    for (int k = 0; k < 4; ++k) {
        int col = t * 4 + k;
        int flag = 0;
        for (int b = 0; b < B_; ++b) flag |= (opcode[b * S_ + col] == 0) ? 1 : 0;
        f[k] = flag; c += flag;
    }
    cnts[t] = c;
    __syncthreads();
    for (int off = 1; off < 1024; off <<= 1) {
        int v = cnts[t];
        int add = (t >= off) ? cnts[t - off] : 0;
        __syncthreads();
        cnts[t] = v + add;
        __syncthreads();
    }
    int base = cnts[t] - c;
    for (int k = 0; k < 4; ++k) {
        if (f[k]) glist[base++] = t * 4 + k;
    }
    if (t == 1023) gcount[0] = cnts[1023];
}

// ---------------- split kernels: fp32 -> bf16 hi + bf16 lo ------------------
__global__ __launch_bounds__(256) void split_x(const float* __restrict__ src,
                                               ushort_t* __restrict__ hi,
                                               ushort_t* __restrict__ lo) {
    int i = blockIdx.x * 256 + threadIdx.x;
    f32x4 v = ((const f32x4*)src)[i];
    us4 h, l;
    for (int e = 0; e < 4; ++e) {
        unsigned short hb = f2bf(v[e]);
        h[e] = hb;
        l[e] = f2bf(v[e] - bf2f(hb));
    }
    ((us4*)hi)[i] = h;
    ((us4*)lo)[i] = l;
}

__global__ __launch_bounds__(256) void split_w4(const float* __restrict__ W0, const float* __restrict__ W1,
                                                const float* __restrict__ W2, const float* __restrict__ W3,
                                                ushort_t* __restrict__ H0, ushort_t* __restrict__ H1,
                                                ushort_t* __restrict__ H2, ushort_t* __restrict__ H3,
                                                ushort_t* __restrict__ L0, ushort_t* __restrict__ L1,
                                                ushort_t* __restrict__ L2, ushort_t* __restrict__ L3) {
    const float* src; ushort_t* hp; ushort_t* lp;
    switch (blockIdx.y) {
        case 0: src = W0; hp = H0; lp = L0; break;
        case 1: src = W1; hp = H1; lp = L1; break;
        case 2: src = W2; hp = H2; lp = L2; break;
        default: src = W3; hp = H3; lp = L3; break;
    }
    int i = blockIdx.x * 256 + threadIdx.x;
    f32x4 v = ((const f32x4*)src)[i];
    us4 h, l;
    for (int e = 0; e < 4; ++e) {
        unsigned short hb = f2bf(v[e]);
        h[e] = hb;
        l[e] = f2bf(v[e] - bf2f(hb));
    }
    ((us4*)hp)[i] = h;
    ((us4*)lp)[i] = l;
}

// ---------------- shared GEMM core: acc = (Ah+Al) @ (Bh+Bl)^T ---------------
// 128x128 tile, BK=32, 4 waves, double-buffered global_load_lds staging.
// LDS layout per buffer (ushort idx): tile(Ah0/Al1/Bh2/Bl3)*4096 + kg*1024 + row*8
__device__ __forceinline__ void gemm_core(const ushort_t* __restrict__ Ah,
                                          const ushort_t* __restrict__ Al,
                                          const ushort_t* __restrict__ Bh,
                                          const ushort_t* __restrict__ Bl,
                                          ushort_t (&LDS)[2][16384],
                                          int m0, int n0, int t,
                                          f32x4 (&acc)[4][4]) {
    const int lane = t & 63, wave = t >> 6;
    const int lrow = lane & 15, lkg = lane >> 4;
    const int wr = wave >> 1, wc = wave & 1;

    const ushort_t* srcs[4] = {Ah, Al, Bh, Bl};
    const int row0[4] = {m0, m0, n0, n0};

    auto stage = [&](int buf, int k0) {
        #pragma unroll
        for (int it = 0; it < 8; ++it) {
            int c = it * 4 + wave;
            int tile = c >> 3;
            int kg = (c >> 1) & 3;
            int r = ((c & 1) << 6) | lane;
            const ushort_t* g = srcs[tile] + (size_t)(row0[tile] + r) * 512 + k0 + kg * 8;
            __builtin_amdgcn_global_load_lds(
                (const __attribute__((address_space(1))) void*)g,
                (__attribute__((address_space(3))) void*)(&LDS[buf][c * 512]),
                16, 0, 0);
        }
    };

    stage(0, 0);
    __syncthreads();

    const int aoff = lkg * 1024 + (wr * 64 + lrow) * 8;
    const int boff = 2 * 4096 + lkg * 1024 + (wc * 64 + lrow) * 8;
    int cur = 0;
    for (int ks = 0; ks < 16; ++ks) {
        if (ks < 15) stage(cur ^ 1, (ks + 1) * 32);
        const ushort_t* Lb = LDS[cur];
        short8 ah[4], al[4], bh[4], bl[4];
        #pragma unroll
        for (int m = 0; m < 4; ++m) {
            ah[m] = *(const short8*)(Lb + aoff + m * 128);
            al[m] = *(const short8*)(Lb + 4096 + aoff + m * 128);
        }
        #pragma unroll
        for (int n = 0; n < 4; ++n) {
            bh[n] = *(const short8*)(Lb + boff + n * 128);
            bl[n] = *(const short8*)(Lb + 4096 + boff + n * 128);
        }
        #pragma unroll
        for (int m = 0; m < 4; ++m)
            #pragma unroll
            for (int n = 0; n < 4; ++n) {
                acc[m][n] = __builtin_amdgcn_mfma_f32_16x16x32_bf16(ah[m], bh[n], acc[m][n], 0, 0, 0);
                acc[m][n] = __builtin_amdgcn_mfma_f32_16x16x32_bf16(al[m], bh[n], acc[m][n], 0, 0, 0);
                acc[m][n] = __builtin_amdgcn_mfma_f32_16x16x32_bf16(ah[m], bl[n], acc[m][n], 0, 0, 0);
            }
        __syncthreads();
        cur ^= 1;
    }
}

// epilogue: D-layout row = lkg*4+r (A-row), col = lrow (B-col)
// mode 0: fp32 out[m*512+n]
// mode 1: bf16 Q row-major [B,H,S,DK], value*scale
// mode 2: K band image: img(b,h,jt) + ((jr*128 + dk*2) ^ ((jr&7)<<4))
// mode 3: Vt band image: img(b,h,jt)+8192 + ((dk*128 + jr*2) ^ ((dk&7)<<4))
__device__ __forceinline__ void gemm_epi(f32x4 (&acc)[4][4], const float* __restrict__ bias,
                                         void* __restrict__ outp, int mode, float scale,
                                         int m0, int n0, int t) {
    const int lane = t & 63, wave = t >> 6;
    const int lrow = lane & 15, lkg = lane >> 4;
    const int wr = wave >> 1, wc = wave & 1;
    for (int m = 0; m < 4; ++m)
        for (int n = 0; n < 4; ++n) {
            int col = n0 + wc * 64 + n * 16 + lrow;
            int row_base = m0 + wr * 64 + m * 16 + lkg * 4;
            float bs = bias[col];
            float vv[4];
            for (int r = 0; r < 4; ++r) vv[r] = (acc[m][n][r] + bs) * scale;
            if (mode == 0) {
                for (int r = 0; r < 4; ++r)
                    ((float*)outp)[(size_t)(row_base + r) * D_ + col] = vv[r];
            } else if (mode == 1) {
                int bb = row_base >> 12, s0 = row_base & (S_ - 1);
                int hh = col >> 6, dk = col & 63;
                for (int r = 0; r < 4; ++r)
                    ((ushort_t*)outp)[(((size_t)(bb * H_ + hh) * S_) + s0 + r) * DK_ + dk] = f2bf(vv[r]);
            } else if (mode == 2) {
                int bb = row_base >> 12, s0 = row_base & (S_ - 1);
                int hh = col >> 6, dk = col & 63;
                for (int r = 0; r < 4; ++r) {
                    int s = s0 + r, jt = s >> 6, jr = s & 63;
                    char* img = (char*)outp + (((size_t)(bb * H_ + hh)) * 64 + jt) * 16384;
                    *(ushort_t*)(img + ((jr * 128 + dk * 2) ^ ((jr & 7) << 4))) = f2bf(vv[r]);
                }
            } else {
                int bb = row_base >> 12, s0 = row_base & (S_ - 1);
                int hh = col >> 6, dk = col & 63;
                int jt = s0 >> 6, jr0 = s0 & 63;
                char* img = (char*)outp + (((size_t)(bb * H_ + hh)) * 64 + jt) * 16384 + 8192;
                us4 pk;
                for (int r = 0; r < 4; ++r) pk[r] = f2bf(vv[r]);
                *(us4*)(img + ((dk * 128 + jr0 * 2) ^ ((dk & 7) << 4))) = pk;
            }
        }
}

// merged Q/K/V projection: z = 0(Q),1(K),2(V)
__global__ __launch_bounds__(256) void gemm_qkv(const ushort_t* __restrict__ xh,
                                                const ushort_t* __restrict__ xl,
                                                const ushort_t* __restrict__ whb,
                                                const ushort_t* __restrict__ wlb,
                                                const float* __restrict__ bq,
                                                const float* __restrict__ bk,
                                                const float* __restrict__ bv,
                                                ushort_t* __restrict__ qb,
                                                char* __restrict__ bandimg) {
    __shared__ ushort_t LDS[2][16384];
    int z = blockIdx.z;
    const ushort_t* Bh = whb + (size_t)z * D_ * D_;
    const ushort_t* Bl = wlb + (size_t)z * D_ * D_;
    const float* bias = (z == 0) ? bq : (z == 1) ? bk : bv;
    int mode = z + 1;
    float scale = (z == 0) ? 0.125f : 1.0f;
    void* outp = (z == 0) ? (void*)qb : (void*)bandimg;
    f32x4 acc[4][4];
    for (int m = 0; m < 4; ++m)
        for (int n = 0; n < 4; ++n)
            acc[m][n] = f32x4{0.f, 0.f, 0.f, 0.f};
    gemm_core(xh, xl, Bh, Bl, LDS, blockIdx.y * 128, blockIdx.x * 128, threadIdx.x, acc);
    gemm_epi(acc, bias, outp, mode, scale, blockIdx.y * 128, blockIdx.x * 128, threadIdx.x);
}

// final projection: fp32 out
__global__ __launch_bounds__(256) void gemm_fin(const ushort_t* __restrict__ Ah,
                                                const ushort_t* __restrict__ Al,
                                                const ushort_t* __restrict__ Bh,
                                                const ushort_t* __restrict__ Bl,
                                                const float* __restrict__ bias,
                                                float* __restrict__ outp) {
    __shared__ ushort_t LDS[2][16384];
    f32x4 acc[4][4];
    for (int m = 0; m < 4; ++m)
        for (int n = 0; n < 4; ++n)
            acc[m][n] = f32x4{0.f, 0.f, 0.f, 0.f};
    gemm_core(Ah, Al, Bh, Bl, LDS, blockIdx.y * 128, blockIdx.x * 128, threadIdx.x, acc);
    gemm_epi(acc, bias, (void*)outp, 0, 1.0f, blockIdx.y * 128, blockIdx.x * 128, threadIdx.x);
}

// ---------------- gather global-column chunks into images -------------------
// grid (NGT, H, B), 256 threads. dst image = [K 8KB][Vt 8KB], same layout as band.
__global__ __launch_bounds__(256) void prep_glob(const char* __restrict__ bandimg,
                                                 char* __restrict__ globimg,
                                                 const int* __restrict__ glist,
                                                 const int* __restrict__ gcount) {
    int G = gcount[0];
    int gc = blockIdx.x;
    if (gc * 64 >= G) return;
    int h = blockIdx.y, b = blockIdx.z;
    int t = threadIdx.x;
    __shared__ int jl[64];
    if (t < 64) { int gi = gc * 64 + t; jl[t] = (gi < G) ? glist[gi] : -1; }
    __syncthreads();
    const size_t bh = (size_t)(b * H_ + h);
    char* dst = globimg + (bh * NGT + gc) * 16384;
    // K rows: thread t copies 32B of column c
    {
        int c = t >> 2, q = t & 3;
        int jj = jl[c];
        #pragma unroll
        for (int p = 0; p < 2; ++p) {
            int o_dst = c * 128 + q * 32 + p * 16;
            short8 val;
            if (jj >= 0) {
                int jr = jj & 63, jt = jj >> 6;
                const char* src = bandimg + (bh * 64 + jt) * 16384;
                val = *(const short8*)(src + ((jr * 128 + q * 32 + p * 16) ^ ((jr & 7) << 4)));
            } else {
                for (int e = 0; e < 8; ++e) val[e] = 0;
            }
            *(short8*)(dst + (o_dst ^ ((c & 7) << 4))) = val;
        }
    }
    // Vt rows: thread t gathers 16 cols of dk-row d
    {
        int d = t >> 2, qq = t & 3;
        short8 v0, v1;
        #pragma unroll 16
        for (int i = 0; i < 16; ++i) {
            int c = qq * 16 + i;
            int jj = jl[c];
            ushort_t val = 0;
            if (jj >= 0) {
                int jr = jj & 63, jt = jj >> 6;
                const char* src = bandimg + (bh * 64 + jt) * 16384 + 8192;
                val = *(const ushort_t*)(src + ((d * 128 + jr * 2) ^ ((d & 7) << 4)));
            }
            if (i < 8) v0[i] = val; else v1[i - 8] = val;
        }
        int o = d * 128 + qq * 32;
        *(short8*)(dst + 8192 + (o ^ ((d & 7) << 4))) = v0;
        *(short8*)(dst + 8192 + ((o + 16) ^ ((d & 7) << 4))) = v1;
    }
}

// ---------------- sparse flash attention, image-fed, double-buffered --------
// 512 threads = 8 waves, 128 q-rows per block.
__global__ __launch_bounds__(512) void attn_mfma2(const ushort_t* __restrict__ Qp,
                                                  const char* __restrict__ bandimg,
                                                  const char* __restrict__ globimg,
                                                  const int* __restrict__ glist,
                                                  const int* __restrict__ gcount,
                                                  ushort_t* __restrict__ AOh,
                                                  ushort_t* __restrict__ AOl) {
    __shared__ char buf[2][16384];           // [K 8KB][Vt 8KB]
    __shared__ ushort_t Ps[8 * 16 * 64];     // per-wave P tile

    const int t = threadIdx.x, lane = t & 63, wave = t >> 6;
    const int lrow = lane & 15, lkg = lane >> 4;
    const int i0 = blockIdx.x * 128, h = blockIdx.y, b = blockIdx.z;
    const size_t headoff = ((size_t)(b * H_ + h)) * S_ * DK_;

    short8 qa[2];
    {
        const ushort_t* qrow = Qp + headoff + (size_t)(i0 + wave * 16 + lrow) * DK_;
        qa[0] = *(const short8*)(qrow + 8 * lkg);
        qa[1] = *(const short8*)(qrow + 32 + 8 * lkg);
    }

    f32x4 Oa[4];
    for (int n = 0; n < 4; ++n) Oa[n] = f32x4{0.f, 0.f, 0.f, 0.f};
    float m_st[4] = {-1e30f, -1e30f, -1e30f, -1e30f};
    float l_st[4] = {0.f, 0.f, 0.f, 0.f};

    int jlo = i0 - WIN_;
    int jt_lo = (jlo < 0) ? 0 : (jlo >> 6);
    int jhi = i0 + 127 + WIN_; if (jhi > S_ - 1) jhi = S_ - 1;
    int jt_hi = jhi >> 6;
    int nband = jt_hi - jt_lo + 1;
    const int G = gcount[0];
    int nglob = (G + 63) >> 6; if (nglob > NGT) nglob = NGT;
    int nchunk = nband + nglob;

    const size_t bh = (size_t)(b * H_ + h);

    auto stage = [&](int ch, int nb) {
        const char* img = (ch < nband)
            ? bandimg + (bh * 64 + (jt_lo + ch)) * 16384
            : globimg + (bh * NGT + (ch - nband)) * 16384;
        #pragma unroll
        for (int i = 0; i < 2; ++i) {
            int seg = wave * 2 + i;
            __builtin_amdgcn_global_load_lds(
                (const __attribute__((address_space(1))) void*)(img + seg * 1024 + lane * 16),
                (__attribute__((address_space(3))) void*)(buf[nb] + seg * 1024),
                16, 0, 0);
        }
    };

    stage(0, 0);
    __syncthreads();

    int cur = 0;
    for (int ch = 0; ch < nchunk; ++ch) {
        if (ch + 1 < nchunk) stage(ch + 1, cur ^ 1);
        const bool isband = ch < nband;
        const int cbase = isband ? (jt_lo + ch) * 64 : 0;
        const int gbase = (ch - nband) * 64;
        const char* Kb = buf[cur];
        const char* Vb = buf[cur] + 8192;

        // column indices for mask (issue global loads early for glob chunks)
        int jj4[4];
        #pragma unroll
        for (int n = 0; n < 4; ++n) {
            int c = n * 16 + lrow;
            if (isband) jj4[n] = cbase + c;
            else { int gi = gbase + c; jj4[n] = (gi < G) ? glist[gi] : -1; }
        }

        // QK^T
        f32x4 sc[4];
        for (int n = 0; n < 4; ++n) sc[n] = f32x4{0.f, 0.f, 0.f, 0.f};
        #pragma unroll
        for (int n = 0; n < 4; ++n) {
            int row = n * 16 + lrow;
            #pragma unroll
            for (int kt = 0; kt < 2; ++kt) {
                int kb = (row * 128 + lkg * 16 + kt * 64) ^ ((row & 7) << 4);
                short8 bk = *(const short8*)(Kb + kb);
                sc[n] = __builtin_amdgcn_mfma_f32_16x16x32_bf16(qa[kt], bk, sc[n], 0, 0, 0);
            }
        }

        // mask + wave-parallel online softmax
        float rmax[4] = {-1e30f, -1e30f, -1e30f, -1e30f};
        #pragma unroll
        for (int n = 0; n < 4; ++n) {
            int jj = jj4[n];
            #pragma unroll
            for (int r = 0; r < 4; ++r) {
                int iq = i0 + wave * 16 + lkg * 4 + r;
                int ad = iq - jj; ad = ad < 0 ? -ad : ad;
                bool allow = isband ? (ad <= WIN_) : ((jj >= 0) && (ad > WIN_));
                float s = allow ? sc[n][r] : -1e30f;
                sc[n][r] = s;
                rmax[r] = fmaxf(rmax[r], s);
            }
        }
        for (int msk = 1; msk < 16; msk <<= 1)
            #pragma unroll
            for (int r = 0; r < 4; ++r)
                rmax[r] = fmaxf(rmax[r], __shfl_xor(rmax[r], msk, 64));

        float fac[4], rsum[4] = {0.f, 0.f, 0.f, 0.f};
        #pragma unroll
        for (int r = 0; r < 4; ++r) {
            float mn = fmaxf(m_st[r], rmax[r]);
            fac[r] = __expf(m_st[r] - mn);
            m_st[r] = mn;
        }
        #pragma unroll
        for (int n = 0; n < 4; ++n)
            #pragma unroll
            for (int r = 0; r < 4; ++r) {
                float p = __expf(sc[n][r] - m_st[r]);
                sc[n][r] = p;
                rsum[r] += p;
            }
        for (int msk = 1; msk < 16; msk <<= 1)
            #pragma unroll
            for (int r = 0; r < 4; ++r)
                rsum[r] += __shfl_xor(rsum[r], msk, 64);
        #pragma unroll
        for (int r = 0; r < 4; ++r) l_st[r] = l_st[r] * fac[r] + rsum[r];

        // P (D-layout) -> wave-private LDS
        ushort_t* Pw = Ps + wave * 1024;
        #pragma unroll
        for (int n = 0; n < 4; ++n)
            #pragma unroll
            for (int r = 0; r < 4; ++r) {
                int row = lkg * 4 + r, col = n * 16 + lrow;
                int pb = (row * 128 + col * 2) ^ ((row & 7) << 4);
                *(ushort_t*)((char*)Pw + pb) = f2bf(sc[n][r]);
            }

        #pragma unroll
        for (int n = 0; n < 4; ++n)
            #pragma unroll
            for (int r = 0; r < 4; ++r) Oa[n][r] *= fac[r];

        short8 pa[2];
        #pragma unroll
        for (int kt = 0; kt < 2; ++kt) {
            int pb = (lrow * 128 + lkg * 16 + kt * 64) ^ ((lrow & 7) << 4);
            pa[kt] = *(const short8*)((char*)Pw + pb);
        }
        #pragma unroll
        for (int n = 0; n < 4; ++n) {
            int row = n * 16 + lrow;
            #pragma unroll
            for (int kt = 0; kt < 2; ++kt) {
                int vb = (row * 128 + lkg * 16 + kt * 64) ^ ((row & 7) << 4);
                short8 bv = *(const short8*)(Vb + vb);
                Oa[n] = __builtin_amdgcn_mfma_f32_16x16x32_bf16(pa[kt], bv, Oa[n], 0, 0, 0);
            }
        }
        __syncthreads();
        cur ^= 1;
    }

    // epilogue: normalize, write hi/lo bf16 AO
    #pragma unroll
    for (int r = 0; r < 4; ++r) {
        int iq = i0 + wave * 16 + lkg * 4 + r;
        float inv = 1.0f / l_st[r];
        #pragma unroll
        for (int n = 0; n < 4; ++n) {
            int dk = n * 16 + lrow;
            float v = Oa[n][r] * inv;
            unsigned short hb = f2bf(v);
            size_t idx = ((size_t)b * S_ + iq) * D_ + h * DK_ + dk;
            AOh[idx] = hb;
            AOl[idx] = f2bf(v - bf2f(hb));
        }
    }
}

// ---------------- launch ----------------------------------------------------
extern "C" void kernel_launch(void* const* d_in, const int* in_sizes, int n_in,
                              void* d_out, int out_size, void* d_ws, size_t ws_size,
                              hipStream_t stream) {
    const float* x      = (const float*)d_in[0];
    const int*   opcode = (const int*)d_in[1];
    const float* Wq = (const float*)d_in[2];
    const float* bq = (const float*)d_in[3];
    const float* Wk = (const float*)d_in[4];
    const float* bk = (const float*)d_in[5];
    const float* Wv = (const float*)d_in[6];
    const float* bv = (const float*)d_in[7];
    const float* Wo = (const float*)d_in[8];
    const float* bo = (const float*)d_in[9];
    float* out = (float*)d_out;

    char* ws = (char*)d_ws;
    const size_t bsd = (size_t)B_ * S_ * D_;
    const size_t bf_bytes = bsd * sizeof(ushort_t);                 // 8.39 MB
    const size_t w_bytes  = (size_t)D_ * D_ * sizeof(ushort_t);     // 0.52 MB

    ushort_t* qb = (ushort_t*)(ws);
    ushort_t* xh = (ushort_t*)(ws + bf_bytes);
    ushort_t* xl = (ushort_t*)(ws + 2 * bf_bytes);
    ushort_t* aoh = xh;   // reuse after V projection
    ushort_t* aol = xl;
    char* wbase = ws + 3 * bf_bytes;
    ushort_t* Wh[4]; ushort_t* Wl[4];
    for (int i = 0; i < 4; ++i) {
        Wh[i] = (ushort_t*)(wbase + i * w_bytes);
        Wl[i] = (ushort_t*)(wbase + (4 + i) * w_bytes);
    }
    char* bandimg = wbase + 8 * w_bytes;                         // 16*64*16KB = 16.78 MB
    char* globimg = bandimg + (size_t)16 * 64 * 16384;           // 16*NGT*16KB = 8.39 MB
    int* glist  = (int*)(globimg + (size_t)16 * NGT * 16384);
    int* gcount = glist + S_;

    build_glist<<<1, 1024, 0, stream>>>(opcode, glist, gcount);
    split_x<<<(int)(bsd / 4 / 256), 256, 0, stream>>>(x, xh, xl);
    split_w4<<<dim3(D_ * D_ / 4 / 256, 4), 256, 0, stream>>>(Wq, Wk, Wv, Wo,
        Wh[0], Wh[1], Wh[2], Wh[3], Wl[0], Wl[1], Wl[2], Wl[3]);

    gemm_qkv<<<dim3(D_ / 128, (B_ * S_) / 128, 3), 256, 0, stream>>>(
        xh, xl, Wh[0], Wl[0], bq, bk, bv, qb, bandimg);

    prep_glob<<<dim3(NGT, H_, B_), 256, 0, stream>>>(bandimg, globimg, glist, gcount);

    attn_mfma2<<<dim3(S_ / 128, H_, B_), 512, 0, stream>>>(
        qb, bandimg, globimg, glist, gcount, aoh, aol);

    gemm_fin<<<dim3(D_ / 128, (B_ * S_) / 128), 256, 0, stream>>>(
        aoh, aol, Wh[3], Wl[3], bo, out);
}

// Round 5
// 218.483 us; speedup vs baseline: 8.1050x; 1.1830x over previous
//
#include <hip/hip_runtime.h>
#include <hip/hip_bf16.h>
#include <math.h>

#define B_ 2
#define S_ 4096
#define D_ 512
#define H_ 8
#define DK_ 64
#define WIN_ 50
#define NGT 32   // max global chunks (2048 cols; E[G]~780)

typedef __attribute__((ext_vector_type(8))) short short8;   // 8 bf16 bit-patterns
typedef __attribute__((ext_vector_type(4))) float f32x4;
typedef __attribute__((ext_vector_type(4))) unsigned short us4;
typedef unsigned short ushort_t;

__device__ __forceinline__ unsigned short f2bf(float f) {
    unsigned u = __builtin_bit_cast(unsigned, f);
    u += 0x7FFF + ((u >> 16) & 1);   // RNE
    return (unsigned short)(u >> 16);
}
__device__ __forceinline__ float bf2f(unsigned short h) {
    return __builtin_bit_cast(float, ((unsigned)h) << 16);
}
__device__ __forceinline__ unsigned pack_bf16(float lo, float hi) {
    // low 16 bits = lo (even k-index), high = hi
    return ((unsigned)f2bf(hi) << 16) | (unsigned)f2bf(lo);
}

// ---------------- K1: build sorted compact list of global (ctrl) columns ----
__global__ __launch_bounds__(1024) void build_glist(const int* __restrict__ opcode,
                                                    int* __restrict__ glist,
                                                    int* __restrict__ gcount) {
    __shared__ int cnts[1024];
    int t = threadIdx.x;
    int f[4]; int c = 0;
    for (int k = 0; k < 4; ++k) {
        int col = t * 4 + k;
        int flag = 0;
        for (int b = 0; b < B_; ++b) flag |= (opcode[b * S_ + col] == 0) ? 1 : 0;
        f[k] = flag; c += flag;
    }
    cnts[t] = c;
    __syncthreads();
    for (int off = 1; off < 1024; off <<= 1) {
        int v = cnts[t];
        int add = (t >= off) ? cnts[t - off] : 0;
        __syncthreads();
        cnts[t] = v + add;
        __syncthreads();
    }
    int base = cnts[t] - c;
    for (int k = 0; k < 4; ++k) {
        if (f[k]) glist[base++] = t * 4 + k;
    }
    if (t == 1023) gcount[0] = cnts[1023];
}

// ---------------- split kernels: fp32 -> bf16 hi + bf16 lo ------------------
__global__ __launch_bounds__(256) void split_x(const float* __restrict__ src,
                                               ushort_t* __restrict__ hi,
                                               ushort_t* __restrict__ lo) {
    int i = blockIdx.x * 256 + threadIdx.x;
    f32x4 v = ((const f32x4*)src)[i];
    us4 h, l;
    for (int e = 0; e < 4; ++e) {
        unsigned short hb = f2bf(v[e]);
        h[e] = hb;
        l[e] = f2bf(v[e] - bf2f(hb));
    }
    ((us4*)hi)[i] = h;
    ((us4*)lo)[i] = l;
}

__global__ __launch_bounds__(256) void split_w4(const float* __restrict__ W0, const float* __restrict__ W1,
                                                const float* __restrict__ W2, const float* __restrict__ W3,
                                                ushort_t* __restrict__ H0, ushort_t* __restrict__ H1,
                                                ushort_t* __restrict__ H2, ushort_t* __restrict__ H3,
                                                ushort_t* __restrict__ L0, ushort_t* __restrict__ L1,
                                                ushort_t* __restrict__ L2, ushort_t* __restrict__ L3) {
    const float* src; ushort_t* hp; ushort_t* lp;
    switch (blockIdx.y) {
        case 0: src = W0; hp = H0; lp = L0; break;
        case 1: src = W1; hp = H1; lp = L1; break;
        case 2: src = W2; hp = H2; lp = L2; break;
        default: src = W3; hp = H3; lp = L3; break;
    }
    int i = blockIdx.x * 256 + threadIdx.x;
    f32x4 v = ((const f32x4*)src)[i];
    us4 h, l;
    for (int e = 0; e < 4; ++e) {
        unsigned short hb = f2bf(v[e]);
        h[e] = hb;
        l[e] = f2bf(v[e] - bf2f(hb));
    }
    ((us4*)hp)[i] = h;
    ((us4*)lp)[i] = l;
}

// ---------------- GEMM epilogue (shared) ------------------------------------
// mode 0: fp32 out[m*512+n]
// mode 1: bf16 Q row-major [B,H,S,DK], value*scale
// mode 2: K band image: img(b,h,jt) + ((jr*128 + dk*2) ^ ((jr&7)<<4))
// mode 3: Vt band image: img(b,h,jt)+8192 + ((dk*128 + jr*2) ^ ((dk&7)<<4))
__device__ __forceinline__ void gemm_epi(f32x4 (&acc)[4][4], const float* __restrict__ bias,
                                         void* __restrict__ outp, int mode, float scale,
                                         int m0, int n0, int t) {
    const int lane = t & 63, wave = t >> 6;
    const int lrow = lane & 15, lkg = lane >> 4;
    const int wr = wave >> 1, wc = wave & 1;
    for (int m = 0; m < 4; ++m)
        for (int n = 0; n < 4; ++n) {
            int col = n0 + wc * 64 + n * 16 + lrow;
            int row_base = m0 + wr * 64 + m * 16 + lkg * 4;
            float bs = bias[col];
            float vv[4];
            for (int r = 0; r < 4; ++r) vv[r] = (acc[m][n][r] + bs) * scale;
            if (mode == 0) {
                for (int r = 0; r < 4; ++r)
                    ((float*)outp)[(size_t)(row_base + r) * D_ + col] = vv[r];
            } else if (mode == 1) {
                int bb = row_base >> 12, s0 = row_base & (S_ - 1);
                int hh = col >> 6, dk = col & 63;
                for (int r = 0; r < 4; ++r)
                    ((ushort_t*)outp)[(((size_t)(bb * H_ + hh) * S_) + s0 + r) * DK_ + dk] = f2bf(vv[r]);
            } else if (mode == 2) {
                int bb = row_base >> 12, s0 = row_base & (S_ - 1);
                int hh = col >> 6, dk = col & 63;
                for (int r = 0; r < 4; ++r) {
                    int s = s0 + r, jt = s >> 6, jr = s & 63;
                    char* img = (char*)outp + (((size_t)(bb * H_ + hh)) * 64 + jt) * 16384;
                    *(ushort_t*)(img + ((jr * 128 + dk * 2) ^ ((jr & 7) << 4))) = f2bf(vv[r]);
                }
            } else {
                int bb = row_base >> 12, s0 = row_base & (S_ - 1);
                int hh = col >> 6, dk = col & 63;
                int jt = s0 >> 6, jr0 = s0 & 63;
                char* img = (char*)outp + (((size_t)(bb * H_ + hh)) * 64 + jt) * 16384 + 8192;
                us4 pk;
                for (int r = 0; r < 4; ++r) pk[r] = f2bf(vv[r]);
                *(us4*)(img + ((dk * 128 + jr0 * 2) ^ ((dk & 7) << 4))) = pk;
            }
        }
}

// ---------------- pure-bf16 GEMM core (QKV projections) ---------------------
// 128x128 tile, BK=32, 4 waves, double-buffered global_load_lds, 2 tiles/step.
// LDS per buffer (ushort idx): tile(A0/B1)*4096 + kg*1024 + row*8
__device__ __forceinline__ void gemm_core1(const ushort_t* __restrict__ A,
                                           const ushort_t* __restrict__ Bw,
                                           ushort_t (&LDS)[2][8192],
                                           int m0, int n0, int t,
                                           f32x4 (&acc)[4][4]) {
    const int lane = t & 63, wave = t >> 6;
    const int lrow = lane & 15, lkg = lane >> 4;
    const int wr = wave >> 1, wc = wave & 1;
    const ushort_t* srcs[2] = {A, Bw};
    const int row0[2] = {m0, n0};

    auto stage = [&](int buf, int k0) {
        #pragma unroll
        for (int it = 0; it < 4; ++it) {
            int c = it * 4 + wave;
            int tile = c >> 3;
            int kg = (c >> 1) & 3;
            int r = ((c & 1) << 6) | lane;
            const ushort_t* g = srcs[tile] + (size_t)(row0[tile] + r) * 512 + k0 + kg * 8;
            __builtin_amdgcn_global_load_lds(
                (const __attribute__((address_space(1))) void*)g,
                (__attribute__((address_space(3))) void*)(&LDS[buf][c * 512]),
                16, 0, 0);
        }
    };

    stage(0, 0);
    __syncthreads();

    const int aoff = lkg * 1024 + (wr * 64 + lrow) * 8;
    const int boff = 4096 + lkg * 1024 + (wc * 64 + lrow) * 8;
    int cur = 0;
    for (int ks = 0; ks < 16; ++ks) {
        if (ks < 15) stage(cur ^ 1, (ks + 1) * 32);
        const ushort_t* Lb = LDS[cur];
        short8 ah[4], bh[4];
        #pragma unroll
        for (int m = 0; m < 4; ++m) ah[m] = *(const short8*)(Lb + aoff + m * 128);
        #pragma unroll
        for (int n = 0; n < 4; ++n) bh[n] = *(const short8*)(Lb + boff + n * 128);
        #pragma unroll
        for (int m = 0; m < 4; ++m)
            #pragma unroll
            for (int n = 0; n < 4; ++n)
                acc[m][n] = __builtin_amdgcn_mfma_f32_16x16x32_bf16(ah[m], bh[n], acc[m][n], 0, 0, 0);
        __syncthreads();
        cur ^= 1;
    }
}

// ---------------- split-3 GEMM core (final projection) ----------------------
__device__ __forceinline__ void gemm_core3(const ushort_t* __restrict__ Ah,
                                           const ushort_t* __restrict__ Al,
                                           const ushort_t* __restrict__ Bh,
                                           const ushort_t* __restrict__ Bl,
                                           ushort_t (&LDS)[2][16384],
                                           int m0, int n0, int t,
                                           f32x4 (&acc)[4][4]) {
    const int lane = t & 63, wave = t >> 6;
    const int lrow = lane & 15, lkg = lane >> 4;
    const int wr = wave >> 1, wc = wave & 1;
    const ushort_t* srcs[4] = {Ah, Al, Bh, Bl};
    const int row0[4] = {m0, m0, n0, n0};

    auto stage = [&](int buf, int k0) {
        #pragma unroll
        for (int it = 0; it < 8; ++it) {
            int c = it * 4 + wave;
            int tile = c >> 3;
            int kg = (c >> 1) & 3;
            int r = ((c & 1) << 6) | lane;
            const ushort_t* g = srcs[tile] + (size_t)(row0[tile] + r) * 512 + k0 + kg * 8;
            __builtin_amdgcn_global_load_lds(
                (const __attribute__((address_space(1))) void*)g,
                (__attribute__((address_space(3))) void*)(&LDS[buf][c * 512]),
                16, 0, 0);
        }
    };

    stage(0, 0);
    __syncthreads();

    const int aoff = lkg * 1024 + (wr * 64 + lrow) * 8;
    const int boff = 2 * 4096 + lkg * 1024 + (wc * 64 + lrow) * 8;
    int cur = 0;
    for (int ks = 0; ks < 16; ++ks) {
        if (ks < 15) stage(cur ^ 1, (ks + 1) * 32);
        const ushort_t* Lb = LDS[cur];
        short8 ah[4], al[4], bh[4], bl[4];
        #pragma unroll
        for (int m = 0; m < 4; ++m) {
            ah[m] = *(const short8*)(Lb + aoff + m * 128);
            al[m] = *(const short8*)(Lb + 4096 + aoff + m * 128);
        }
        #pragma unroll
        for (int n = 0; n < 4; ++n) {
            bh[n] = *(const short8*)(Lb + boff + n * 128);
            bl[n] = *(const short8*)(Lb + 4096 + boff + n * 128);
        }
        #pragma unroll
        for (int m = 0; m < 4; ++m)
            #pragma unroll
            for (int n = 0; n < 4; ++n) {
                acc[m][n] = __builtin_amdgcn_mfma_f32_16x16x32_bf16(ah[m], bh[n], acc[m][n], 0, 0, 0);
                acc[m][n] = __builtin_amdgcn_mfma_f32_16x16x32_bf16(al[m], bh[n], acc[m][n], 0, 0, 0);
                acc[m][n] = __builtin_amdgcn_mfma_f32_16x16x32_bf16(ah[m], bl[n], acc[m][n], 0, 0, 0);
            }
        __syncthreads();
        cur ^= 1;
    }
}

// merged Q/K/V projection (pure bf16): z = 0(Q),1(K),2(V)
__global__ __launch_bounds__(256) void gemm_qkv(const ushort_t* __restrict__ xh,
                                                const ushort_t* __restrict__ whb,
                                                const float* __restrict__ bq,
                                                const float* __restrict__ bk,
                                                const float* __restrict__ bv,
                                                ushort_t* __restrict__ qb,
                                                char* __restrict__ bandimg) {
    __shared__ ushort_t LDS[2][8192];
    int z = blockIdx.z;
    const ushort_t* Bh = whb + (size_t)z * D_ * D_;
    const float* bias = (z == 0) ? bq : (z == 1) ? bk : bv;
    int mode = z + 1;
    float scale = (z == 0) ? 0.125f : 1.0f;
    void* outp = (z == 0) ? (void*)qb : (void*)bandimg;
    f32x4 acc[4][4];
    for (int m = 0; m < 4; ++m)
        for (int n = 0; n < 4; ++n)
            acc[m][n] = f32x4{0.f, 0.f, 0.f, 0.f};
    gemm_core1(xh, Bh, LDS, blockIdx.y * 128, blockIdx.x * 128, threadIdx.x, acc);
    gemm_epi(acc, bias, outp, mode, scale, blockIdx.y * 128, blockIdx.x * 128, threadIdx.x);
}

// final projection: split-3, fp32 out
__global__ __launch_bounds__(256) void gemm_fin(const ushort_t* __restrict__ Ah,
                                                const ushort_t* __restrict__ Al,
                                                const ushort_t* __restrict__ Bh,
                                                const ushort_t* __restrict__ Bl,
                                                const float* __restrict__ bias,
                                                float* __restrict__ outp) {
    __shared__ ushort_t LDS[2][16384];
    f32x4 acc[4][4];
    for (int m = 0; m < 4; ++m)
        for (int n = 0; n < 4; ++n)
            acc[m][n] = f32x4{0.f, 0.f, 0.f, 0.f};
    gemm_core3(Ah, Al, Bh, Bl, LDS, blockIdx.y * 128, blockIdx.x * 128, threadIdx.x, acc);
    gemm_epi(acc, bias, (void*)outp, 0, 1.0f, blockIdx.y * 128, blockIdx.x * 128, threadIdx.x);
}

// ---------------- gather global-column chunks into images -------------------
__global__ __launch_bounds__(256) void prep_glob(const char* __restrict__ bandimg,
                                                 char* __restrict__ globimg,
                                                 const int* __restrict__ glist,
                                                 const int* __restrict__ gcount) {
    int G = gcount[0];
    int gc = blockIdx.x;
    if (gc * 64 >= G) return;
    int h = blockIdx.y, b = blockIdx.z;
    int t = threadIdx.x;
    __shared__ int jl[64];
    if (t < 64) { int gi = gc * 64 + t; jl[t] = (gi < G) ? glist[gi] : -1; }
    __syncthreads();
    const size_t bh = (size_t)(b * H_ + h);
    char* dst = globimg + (bh * NGT + gc) * 16384;
    {
        int c = t >> 2, q = t & 3;
        int jj = jl[c];
        #pragma unroll
        for (int p = 0; p < 2; ++p) {
            int o_dst = c * 128 + q * 32 + p * 16;
            short8 val;
            if (jj >= 0) {
                int jr = jj & 63, jt = jj >> 6;
                const char* src = bandimg + (bh * 64 + jt) * 16384;
                val = *(const short8*)(src + ((jr * 128 + q * 32 + p * 16) ^ ((jr & 7) << 4)));
            } else {
                for (int e = 0; e < 8; ++e) val[e] = 0;
            }
            *(short8*)(dst + (o_dst ^ ((c & 7) << 4))) = val;
        }
    }
    {
        int d = t >> 2, qq = t & 3;
        short8 v0, v1;
        #pragma unroll 16
        for (int i = 0; i < 16; ++i) {
            int c = qq * 16 + i;
            int jj = jl[c];
            ushort_t val = 0;
            if (jj >= 0) {
                int jr = jj & 63, jt = jj >> 6;
                const char* src = bandimg + (bh * 64 + jt) * 16384 + 8192;
                val = *(const ushort_t*)(src + ((d * 128 + jr * 2) ^ ((d & 7) << 4)));
            }
            if (i < 8) v0[i] = val; else v1[i - 8] = val;
        }
        int o = d * 128 + qq * 32;
        *(short8*)(dst + 8192 + (o ^ ((d & 7) << 4))) = v0;
        *(short8*)(dst + 8192 + ((o + 16) ^ ((d & 7) << 4))) = v1;
    }
}

// ---------------- sparse flash attention, swapped-operand MFMA --------------
// D-layout col = q (lane&15): each lane owns one q-row -> lane-local softmax.
__global__ __launch_bounds__(512) void attn_mfma3(const ushort_t* __restrict__ Qp,
                                                  const char* __restrict__ bandimg,
                                                  const char* __restrict__ globimg,
                                                  const int* __restrict__ glist,
                                                  const int* __restrict__ gcount,
                                                  ushort_t* __restrict__ AOh,
                                                  ushort_t* __restrict__ AOl) {
    __shared__ char buf[2][16384];           // [K 8KB][Vt 8KB]
    __shared__ int jl[2][64];
    __shared__ ushort_t Ps[8 * 16 * 64];     // per-wave P^T: row=q (16), 64 j, swizzled

    const int t = threadIdx.x, lane = t & 63, wave = t >> 6;
    const int q = lane & 15, g = lane >> 4;
    const int i0 = blockIdx.x * 128, h = blockIdx.y, b = blockIdx.z;
    const size_t headoff = ((size_t)(b * H_ + h)) * S_ * DK_;
    const int iq = i0 + wave * 16 + q;

    // Q as B-fragment: lane holds Q[q][dk = g*8+e (+32*kt)]
    short8 qa[2];
    {
        const ushort_t* qrow = Qp + headoff + (size_t)iq * DK_;
        qa[0] = *(const short8*)(qrow + 8 * g);
        qa[1] = *(const short8*)(qrow + 32 + 8 * g);
    }

    f32x4 Oa[4];   // Oa[n][r] = O[dk = 16n+4g+r][q]
    for (int n = 0; n < 4; ++n) Oa[n] = f32x4{0.f, 0.f, 0.f, 0.f};
    float m_st = -1e30f, l_st = 0.f;

    int jlo = i0 - WIN_;
    int jt_lo = (jlo < 0) ? 0 : (jlo >> 6);
    int jhi = i0 + 127 + WIN_; if (jhi > S_ - 1) jhi = S_ - 1;
    int jt_hi = jhi >> 6;
    int nband = jt_hi - jt_lo + 1;
    const int G = gcount[0];
    int nglob = (G + 63) >> 6; if (nglob > NGT) nglob = NGT;
    int nchunk = nband + nglob;

    const size_t bh = (size_t)(b * H_ + h);

    auto stage = [&](int ch, int nb) {
        const char* img = (ch < nband)
            ? bandimg + (bh * 64 + (jt_lo + ch)) * 16384
            : globimg + (bh * NGT + (ch - nband)) * 16384;
        #pragma unroll
        for (int i = 0; i < 2; ++i) {
            int seg = wave * 2 + i;
            __builtin_amdgcn_global_load_lds(
                (const __attribute__((address_space(1))) void*)(img + seg * 1024 + lane * 16),
                (__attribute__((address_space(3))) void*)(buf[nb] + seg * 1024),
                16, 0, 0);
        }
        if (t < 64) {
            int j;
            if (ch < nband) j = (jt_lo + ch) * 64 + t;
            else { int gi = (ch - nband) * 64 + t; j = (gi < G) ? glist[gi] : -1; }
            jl[nb][t] = j;
        }
    };

    stage(0, 0);
    __syncthreads();

    int cur = 0;
    for (int ch = 0; ch < nchunk; ++ch) {
        if (ch + 1 < nchunk) stage(ch + 1, cur ^ 1);
        const bool isband = ch < nband;
        const char* Kb = buf[cur];
        const char* Vb = buf[cur] + 8192;

        // QK^T swapped: sc[n][r] = S[j = 16n+4g+r][q]
        f32x4 sc[4];
        for (int n = 0; n < 4; ++n) sc[n] = f32x4{0.f, 0.f, 0.f, 0.f};
        #pragma unroll
        for (int n = 0; n < 4; ++n) {
            int row = n * 16 + q;   // K image row (j), A-frag row index = lane&15
            #pragma unroll
            for (int kt = 0; kt < 2; ++kt) {
                int kb = (row * 128 + g * 16 + kt * 64) ^ ((row & 7) << 4);
                short8 ka = *(const short8*)(Kb + kb);
                sc[n] = __builtin_amdgcn_mfma_f32_16x16x32_bf16(ka, qa[kt], sc[n], 0, 0, 0);
            }
        }

        // mask + lane-local online softmax
        float pm = -1e30f;
        #pragma unroll
        for (int n = 0; n < 4; ++n) {
            int4 J = *(const int4*)(&jl[cur][n * 16 + g * 4]);
            int js[4] = {J.x, J.y, J.z, J.w};
            #pragma unroll
            for (int r = 0; r < 4; ++r) {
                int jj = js[r];
                int ad = iq - jj; ad = ad < 0 ? -ad : ad;
                bool allow = (jj >= 0) && (isband ? (ad <= WIN_) : (ad > WIN_));
                float s = allow ? sc[n][r] : -1e30f;
                sc[n][r] = s;
                pm = fmaxf(pm, s);
            }
        }
        pm = fmaxf(pm, __shfl_xor(pm, 16, 64));
        pm = fmaxf(pm, __shfl_xor(pm, 32, 64));

        bool skip = __all(pm <= m_st);   // exact: fac would be 1
        float fac = 1.0f;
        if (!skip) {
            float mn = fmaxf(m_st, pm);
            fac = __expf(m_st - mn);
            m_st = mn;
        }
        float rs = 0.f;
        #pragma unroll
        for (int n = 0; n < 4; ++n)
            #pragma unroll
            for (int r = 0; r < 4; ++r) {
                float p = __expf(sc[n][r] - m_st);
                sc[n][r] = p;
                rs += p;
            }
        rs += __shfl_xor(rs, 16, 64);
        rs += __shfl_xor(rs, 32, 64);
        l_st = skip ? (l_st + rs) : (l_st * fac + rs);

        // P^T -> wave-private LDS: row=q, col=j, packed dword pairs
        ushort_t* Pw = Ps + wave * 1024;
        #pragma unroll
        for (int n = 0; n < 4; ++n)
            #pragma unroll
            for (int hh = 0; hh < 2; ++hh) {
                unsigned pk = pack_bf16(sc[n][2 * hh], sc[n][2 * hh + 1]);
                int off = (q * 128 + n * 32 + g * 8 + hh * 4) ^ ((q & 7) << 4);
                *(unsigned*)((char*)Pw + off) = pk;
            }

        if (!skip) {
            #pragma unroll
            for (int n = 0; n < 4; ++n)
                #pragma unroll
                for (int r = 0; r < 4; ++r) Oa[n][r] *= fac;
        }

        // P as B-fragment: lane holds P[q][j = g*8+e (+32*kt)]
        short8 pa[2];
        #pragma unroll
        for (int kt = 0; kt < 2; ++kt) {
            int pb = (q * 128 + g * 16 + kt * 64) ^ ((q & 7) << 4);
            pa[kt] = *(const short8*)((char*)Pw + pb);
        }
        // PV swapped: Oa[n] += Vt_frag(n) * pa
        #pragma unroll
        for (int n = 0; n < 4; ++n) {
            int row = n * 16 + q;   // Vt image row (dk)
            #pragma unroll
            for (int kt = 0; kt < 2; ++kt) {
                int vb = (row * 128 + g * 16 + kt * 64) ^ ((row & 7) << 4);
                short8 va = *(const short8*)(Vb + vb);
                Oa[n] = __builtin_amdgcn_mfma_f32_16x16x32_bf16(va, pa[kt], Oa[n], 0, 0, 0);
            }
        }
        __syncthreads();
        cur ^= 1;
    }

    // epilogue: normalize, write hi/lo bf16 AO (4 consecutive dk per vector)
    float inv = 1.0f / l_st;
    #pragma unroll
    for (int n = 0; n < 4; ++n) {
        us4 ph, pl;
        #pragma unroll
        for (int r = 0; r < 4; ++r) {
            float v = Oa[n][r] * inv;
            unsigned short hb = f2bf(v);
            ph[r] = hb;
            pl[r] = f2bf(v - bf2f(hb));
        }
        size_t base = ((size_t)b * S_ + iq) * D_ + h * DK_ + (n * 16 + g * 4);
        *(us4*)(AOh + base) = ph;
        *(us4*)(AOl + base) = pl;
    }
}

// ---------------- launch ----------------------------------------------------
extern "C" void kernel_launch(void* const* d_in, const int* in_sizes, int n_in,
                              void* d_out, int out_size, void* d_ws, size_t ws_size,
                              hipStream_t stream) {
    const float* x      = (const float*)d_in[0];
    const int*   opcode = (const int*)d_in[1];
    const float* Wq = (const float*)d_in[2];
    const float* bq = (const float*)d_in[3];
    const float* Wk = (const float*)d_in[4];
    const float* bk = (const float*)d_in[5];
    const float* Wv = (const float*)d_in[6];
    const float* bv = (const float*)d_in[7];
    const float* Wo = (const float*)d_in[8];
    const float* bo = (const float*)d_in[9];
    float* out = (float*)d_out;

    char* ws = (char*)d_ws;
    const size_t bsd = (size_t)B_ * S_ * D_;
    const size_t bf_bytes = bsd * sizeof(ushort_t);                 // 8.39 MB
    const size_t w_bytes  = (size_t)D_ * D_ * sizeof(ushort_t);     // 0.52 MB

    ushort_t* qb = (ushort_t*)(ws);
    ushort_t* xh = (ushort_t*)(ws + bf_bytes);
    ushort_t* xl = (ushort_t*)(ws + 2 * bf_bytes);
    ushort_t* aoh = xh;   // reuse after projections
    ushort_t* aol = xl;
    char* wbase = ws + 3 * bf_bytes;
    ushort_t* Wh[4]; ushort_t* Wl[4];
    for (int i = 0; i < 4; ++i) {
        Wh[i] = (ushort_t*)(wbase + i * w_bytes);
        Wl[i] = (ushort_t*)(wbase + (4 + i) * w_bytes);
    }
    char* bandimg = wbase + 8 * w_bytes;                         // 16*64*16KB
    char* globimg = bandimg + (size_t)16 * 64 * 16384;           // 16*NGT*16KB
    int* glist  = (int*)(globimg + (size_t)16 * NGT * 16384);
    int* gcount = glist + S_;

    build_glist<<<1, 1024, 0, stream>>>(opcode, glist, gcount);
    split_x<<<(int)(bsd / 4 / 256), 256, 0, stream>>>(x, xh, xl);
    split_w4<<<dim3(D_ * D_ / 4 / 256, 4), 256, 0, stream>>>(Wq, Wk, Wv, Wo,
        Wh[0], Wh[1], Wh[2], Wh[3], Wl[0], Wl[1], Wl[2], Wl[3]);

    gemm_qkv<<<dim3(D_ / 128, (B_ * S_) / 128, 3), 256, 0, stream>>>(
        xh, Wh[0], bq, bk, bv, qb, bandimg);

    prep_glob<<<dim3(NGT, H_, B_), 256, 0, stream>>>(bandimg, globimg, glist, gcount);

    attn_mfma3<<<dim3(S_ / 128, H_, B_), 512, 0, stream>>>(
        qb, bandimg, globimg, glist, gcount, aoh, aol);

    gemm_fin<<<dim3(D_ / 128, (B_ * S_) / 128), 256, 0, stream>>>(
        aoh, aol, Wh[3], Wl[3], bo, out);
}

// Round 6
// 204.669 us; speedup vs baseline: 8.6520x; 1.0675x over previous
//
#include <hip/hip_runtime.h>
#include <hip/hip_bf16.h>
#include <math.h>

#define B_ 2
#define S_ 4096
#define D_ 512
#define H_ 8
#define DK_ 64
#define WIN_ 50
#define NGT 32   // max global chunks (2048 cols; E[G]~780)
#define QSCALE 0.18033688011112042f   // 0.125 * log2(e): softmax in log2 domain

typedef __attribute__((ext_vector_type(8))) short short8;   // 8 bf16 bit-patterns
typedef __attribute__((ext_vector_type(4))) float f32x4;
typedef __attribute__((ext_vector_type(4))) unsigned short us4;
typedef unsigned short ushort_t;

__device__ __forceinline__ unsigned short f2bf(float f) {
    unsigned u = __builtin_bit_cast(unsigned, f);
    u += 0x7FFF + ((u >> 16) & 1);   // RNE
    return (unsigned short)(u >> 16);
}
__device__ __forceinline__ float bf2f(unsigned short h) {
    return __builtin_bit_cast(float, ((unsigned)h) << 16);
}
__device__ __forceinline__ unsigned cvt_pk_bf16(float lo, float hi) {
    unsigned r;
    asm("v_cvt_pk_bf16_f32 %0, %1, %2" : "=v"(r) : "v"(lo), "v"(hi));
    return r;
}

// ---------------- fused prep: split x (hi), split W (hi; lo for Wo), glist --
__global__ __launch_bounds__(256) void prep_all(const float* __restrict__ x,
                                                const float* __restrict__ W0,
                                                const float* __restrict__ W1,
                                                const float* __restrict__ W2,
                                                const float* __restrict__ W3,
                                                const int* __restrict__ opcode,
                                                ushort_t* __restrict__ xh,
                                                ushort_t* __restrict__ whb,
                                                ushort_t* __restrict__ wol,
                                                int* __restrict__ glist,
                                                int* __restrict__ gcount) {
    const int bid = blockIdx.x;
    const int t = threadIdx.x;
    if (bid < 4096) {                       // x -> bf16 hi only
        int i = bid * 256 + t;
        f32x4 v = ((const f32x4*)x)[i];
        us4 hv;
        for (int e = 0; e < 4; ++e) hv[e] = f2bf(v[e]);
        ((us4*)xh)[i] = hv;
    } else if (bid < 5120) {                // weights
        int b2 = bid - 4096;
        int wz = b2 >> 8, inner = b2 & 255;
        const float* src = (wz == 0) ? W0 : (wz == 1) ? W1 : (wz == 2) ? W2 : W3;
        int i = inner * 256 + t;
        f32x4 v = ((const f32x4*)src)[i];
        us4 hv, lv;
        for (int e = 0; e < 4; ++e) {
            unsigned short hb = f2bf(v[e]);
            hv[e] = hb;
            lv[e] = f2bf(v[e] - bf2f(hb));
        }
        ((us4*)(whb + (size_t)wz * D_ * D_))[i] = hv;
        if (wz == 3) ((us4*)wol)[i] = lv;
    } else {                                // glist scan (sorted compact)
        __shared__ int cnts[256];
        unsigned fl = 0; int c = 0;
        for (int k = 0; k < 16; ++k) {
            int col = t * 16 + k;
            int flag = (opcode[col] == 0) | (opcode[S_ + col] == 0);
            fl |= (unsigned)flag << k; c += flag;
        }
        cnts[t] = c;
        __syncthreads();
        for (int off = 1; off < 256; off <<= 1) {
            int v = cnts[t];
            int a = (t >= off) ? cnts[t - off] : 0;
            __syncthreads();
            cnts[t] = v + a;
            __syncthreads();
        }
        int base = cnts[t] - c;
        for (int k = 0; k < 16; ++k)
            if ((fl >> k) & 1) glist[base++] = t * 16 + k;
        if (t == 255) gcount[0] = cnts[255];
    }
}

// ---------------- pure-bf16 GEMM core: dot over k of A-rows x B-rows --------
// 128x128 tile, BK=32, 4 waves, double-buffered global_load_lds.
// LDS per buffer (ushort idx): tile(A0/B1)*4096 + kg*1024 + row*8
__device__ __forceinline__ void gemm_core1(const ushort_t* __restrict__ A,
                                           const ushort_t* __restrict__ Bw,
                                           ushort_t (&LDS)[2][8192],
                                           int m0, int n0, int t,
                                           f32x4 (&acc)[4][4]) {
    const int lane = t & 63, wave = t >> 6;
    const int lrow = lane & 15, lkg = lane >> 4;
    const int wr = wave >> 1, wc = wave & 1;
    const ushort_t* srcs[2] = {A, Bw};
    const int row0[2] = {m0, n0};

    auto stage = [&](int buf, int k0) {
        #pragma unroll
        for (int it = 0; it < 4; ++it) {
            int c = it * 4 + wave;
            int tile = c >> 3;
            int kg = (c >> 1) & 3;
            int r = ((c & 1) << 6) | lane;
            const ushort_t* g = srcs[tile] + (size_t)(row0[tile] + r) * 512 + k0 + kg * 8;
            __builtin_amdgcn_global_load_lds(
                (const __attribute__((address_space(1))) void*)g,
                (__attribute__((address_space(3))) void*)(&LDS[buf][c * 512]),
                16, 0, 0);
        }
    };

    stage(0, 0);
    __syncthreads();

    const int aoff = lkg * 1024 + (wr * 64 + lrow) * 8;
    const int boff = 4096 + lkg * 1024 + (wc * 64 + lrow) * 8;
    int cur = 0;
    for (int ks = 0; ks < 16; ++ks) {
        if (ks < 15) stage(cur ^ 1, (ks + 1) * 32);
        const ushort_t* Lb = LDS[cur];
        short8 ah[4], bh[4];
        #pragma unroll
        for (int m = 0; m < 4; ++m) ah[m] = *(const short8*)(Lb + aoff + m * 128);
        #pragma unroll
        for (int n = 0; n < 4; ++n) bh[n] = *(const short8*)(Lb + boff + n * 128);
        #pragma unroll
        for (int m = 0; m < 4; ++m)
            #pragma unroll
            for (int n = 0; n < 4; ++n)
                acc[m][n] = __builtin_amdgcn_mfma_f32_16x16x32_bf16(ah[m], bh[n], acc[m][n], 0, 0, 0);
        __syncthreads();
        cur ^= 1;
    }
}

// ---------------- split-3 GEMM core (final projection, swapped) -------------
__device__ __forceinline__ void gemm_core3(const ushort_t* __restrict__ Ah,
                                           const ushort_t* __restrict__ Al,
                                           const ushort_t* __restrict__ Bh,
                                           const ushort_t* __restrict__ Bl,
                                           ushort_t (&LDS)[2][16384],
                                           int m0, int n0, int t,
                                           f32x4 (&acc)[4][4]) {
    const int lane = t & 63, wave = t >> 6;
    const int lrow = lane & 15, lkg = lane >> 4;
    const int wr = wave >> 1, wc = wave & 1;
    const ushort_t* srcs[4] = {Ah, Al, Bh, Bl};
    const int row0[4] = {m0, m0, n0, n0};

    auto stage = [&](int buf, int k0) {
        #pragma unroll
        for (int it = 0; it < 8; ++it) {
            int c = it * 4 + wave;
            int tile = c >> 3;
            int kg = (c >> 1) & 3;
            int r = ((c & 1) << 6) | lane;
            const ushort_t* g = srcs[tile] + (size_t)(row0[tile] + r) * 512 + k0 + kg * 8;
            __builtin_amdgcn_global_load_lds(
                (const __attribute__((address_space(1))) void*)g,
                (__attribute__((address_space(3))) void*)(&LDS[buf][c * 512]),
                16, 0, 0);
        }
    };

    stage(0, 0);
    __syncthreads();

    const int aoff = lkg * 1024 + (wr * 64 + lrow) * 8;
    const int boff = 2 * 4096 + lkg * 1024 + (wc * 64 + lrow) * 8;
    int cur = 0;
    for (int ks = 0; ks < 16; ++ks) {
        if (ks < 15) stage(cur ^ 1, (ks + 1) * 32);
        const ushort_t* Lb = LDS[cur];
        short8 ah[4], al[4], bh[4], bl[4];
        #pragma unroll
        for (int m = 0; m < 4; ++m) {
            ah[m] = *(const short8*)(Lb + aoff + m * 128);
            al[m] = *(const short8*)(Lb + 4096 + aoff + m * 128);
        }
        #pragma unroll
        for (int n = 0; n < 4; ++n) {
            bh[n] = *(const short8*)(Lb + boff + n * 128);
            bl[n] = *(const short8*)(Lb + 4096 + boff + n * 128);
        }
        #pragma unroll
        for (int m = 0; m < 4; ++m)
            #pragma unroll
            for (int n = 0; n < 4; ++n) {
                acc[m][n] = __builtin_amdgcn_mfma_f32_16x16x32_bf16(ah[m], bh[n], acc[m][n], 0, 0, 0);
                acc[m][n] = __builtin_amdgcn_mfma_f32_16x16x32_bf16(al[m], bh[n], acc[m][n], 0, 0, 0);
                acc[m][n] = __builtin_amdgcn_mfma_f32_16x16x32_bf16(ah[m], bl[n], acc[m][n], 0, 0, 0);
            }
        __syncthreads();
        cur ^= 1;
    }
}

// merged Q/K/V projection: z=0 Q (swapped), z=1 K (swapped), z=2 V (normal)
__global__ __launch_bounds__(256) void gemm_qkv(const ushort_t* __restrict__ xh,
                                                const ushort_t* __restrict__ whb,
                                                const float* __restrict__ bq,
                                                const float* __restrict__ bk,
                                                const float* __restrict__ bv,
                                                ushort_t* __restrict__ qb,
                                                char* __restrict__ bandimg) {
    __shared__ ushort_t LDS[2][8192];
    const int z = blockIdx.z;
    const int t = threadIdx.x;
    const ushort_t* Wz = whb + (size_t)z * D_ * D_;
    const int lane = t & 63, wave = t >> 6;
    const int lrow = lane & 15, lkg = lane >> 4;
    const int wr = wave >> 1, wc = wave & 1;

    f32x4 acc[4][4];
    for (int m = 0; m < 4; ++m)
        for (int n = 0; n < 4; ++n)
            acc[m][n] = f32x4{0.f, 0.f, 0.f, 0.f};

    if (z == 2) {
        // V: A = x rows (s), B = Wv rows (d)
        const int m0 = blockIdx.y * 128, n0 = blockIdx.x * 128;
        gemm_core1(xh, Wz, LDS, m0, n0, t, acc);
        for (int m = 0; m < 4; ++m) {
            int s_base = m0 + wr * 64 + m * 16 + lkg * 4;
            int bb = s_base >> 12, s0 = s_base & (S_ - 1);
            int jt = s0 >> 6, jr0 = s0 & 63;
            for (int n = 0; n < 4; ++n) {
                int col = n0 + wc * 64 + n * 16 + lrow;
                float bs = bv[col];
                int hh = col >> 6, dk = col & 63;
                us4 pk;
                for (int r = 0; r < 4; ++r) pk[r] = f2bf(acc[m][n][r] + bs);
                char* img = bandimg + (((size_t)(bb * H_ + hh)) * 64 + jt) * 16384 + 8192;
                *(us4*)(img + ((dk * 128 + jr0 * 2) ^ ((dk & 7) << 4))) = pk;
            }
        }
    } else {
        // Q/K swapped: A = W rows (d), B = x rows (s)
        const int m0 = blockIdx.x * 128, n0 = blockIdx.y * 128;
        gemm_core1(Wz, xh, LDS, m0, n0, t, acc);
        const float* bias = (z == 0) ? bq : bk;
        for (int m = 0; m < 4; ++m) {
            int d_base = m0 + wr * 64 + m * 16 + lkg * 4;
            f32x4 b4 = *(const f32x4*)(bias + d_base);
            int hh = d_base >> 6, dkb = d_base & 63;
            for (int n = 0; n < 4; ++n) {
                int s = n0 + wc * 64 + n * 16 + lrow;
                int bb = s >> 12, sl = s & (S_ - 1);
                us4 pk;
                if (z == 0) {
                    for (int r = 0; r < 4; ++r) pk[r] = f2bf((acc[m][n][r] + b4[r]) * QSCALE);
                    *(us4*)(qb + (((size_t)(bb * H_ + hh) * S_) + sl) * DK_ + dkb) = pk;
                } else {
                    for (int r = 0; r < 4; ++r) pk[r] = f2bf(acc[m][n][r] + b4[r]);
                    int jt = sl >> 6, jr = sl & 63;
                    char* img = bandimg + (((size_t)(bb * H_ + hh)) * 64 + jt) * 16384;
                    *(us4*)(img + ((jr * 128 + dkb * 2) ^ ((jr & 7) << 4))) = pk;
                }
            }
        }
    }
}

// final projection (swapped, split-3): out[s][d] = ao @ Wo^T + bo, fp32
__global__ __launch_bounds__(256) void gemm_fin(const ushort_t* __restrict__ Woh,
                                                const ushort_t* __restrict__ Wol,
                                                const ushort_t* __restrict__ aoh,
                                                const ushort_t* __restrict__ aol,
                                                const float* __restrict__ bias,
                                                float* __restrict__ outp) {
    __shared__ ushort_t LDS[2][16384];
    const int t = threadIdx.x;
    const int lane = t & 63, wave = t >> 6;
    const int lrow = lane & 15, lkg = lane >> 4;
    const int wr = wave >> 1, wc = wave & 1;
    const int m0 = blockIdx.x * 128, n0 = blockIdx.y * 128;

    f32x4 acc[4][4];
    for (int m = 0; m < 4; ++m)
        for (int n = 0; n < 4; ++n)
            acc[m][n] = f32x4{0.f, 0.f, 0.f, 0.f};
    gemm_core3(Woh, Wol, aoh, aol, LDS, m0, n0, t, acc);

    for (int m = 0; m < 4; ++m) {
        int d_base = m0 + wr * 64 + m * 16 + lkg * 4;
        f32x4 b4 = *(const f32x4*)(bias + d_base);
        for (int n = 0; n < 4; ++n) {
            int s = n0 + wc * 64 + n * 16 + lrow;
            f32x4 o;
            for (int r = 0; r < 4; ++r) o[r] = acc[m][n][r] + b4[r];
            *(f32x4*)(outp + (size_t)s * D_ + d_base) = o;
        }
    }
}

// ---------------- gather global-column chunks into images -------------------
__global__ __launch_bounds__(256) void prep_glob(const char* __restrict__ bandimg,
                                                 char* __restrict__ globimg,
                                                 const int* __restrict__ glist,
                                                 const int* __restrict__ gcount) {
    int G = gcount[0];
    int gc = blockIdx.x;
    if (gc * 64 >= G) return;
    int h = blockIdx.y, b = blockIdx.z;
    int t = threadIdx.x;
    __shared__ int jl[64];
    if (t < 64) { int gi = gc * 64 + t; jl[t] = (gi < G) ? glist[gi] : -1; }
    __syncthreads();
    const size_t bh = (size_t)(b * H_ + h);
    char* dst = globimg + (bh * NGT + gc) * 16384;
    {
        int c = t >> 2, q = t & 3;
        int jj = jl[c];
        #pragma unroll
        for (int p = 0; p < 2; ++p) {
            int o_dst = c * 128 + q * 32 + p * 16;
            short8 val;
            if (jj >= 0) {
                int jr = jj & 63, jt = jj >> 6;
                const char* src = bandimg + (bh * 64 + jt) * 16384;
                val = *(const short8*)(src + ((jr * 128 + q * 32 + p * 16) ^ ((jr & 7) << 4)));
            } else {
                for (int e = 0; e < 8; ++e) val[e] = 0;
            }
            *(short8*)(dst + (o_dst ^ ((c & 7) << 4))) = val;
        }
    }
    {
        int d = t >> 2, qq = t & 3;
        short8 v0, v1;
        #pragma unroll 16
        for (int i = 0; i < 16; ++i) {
            int c = qq * 16 + i;
            int jj = jl[c];
            ushort_t val = 0;
            if (jj >= 0) {
                int jr = jj & 63, jt = jj >> 6;
                const char* src = bandimg + (bh * 64 + jt) * 16384 + 8192;
                val = *(const ushort_t*)(src + ((d * 128 + jr * 2) ^ ((d & 7) << 4)));
            }
            if (i < 8) v0[i] = val; else v1[i - 8] = val;
        }
        int o = d * 128 + qq * 32;
        *(short8*)(dst + 8192 + (o ^ ((d & 7) << 4))) = v0;
        *(short8*)(dst + 8192 + ((o + 16) ^ ((d & 7) << 4))) = v1;
    }
}

// ---------------- sparse flash attention, log2-softmax, cvt_pk --------------
__global__ __launch_bounds__(512) void attn_mfma4(const ushort_t* __restrict__ Qp,
                                                  const char* __restrict__ bandimg,
                                                  const char* __restrict__ globimg,
                                                  const int* __restrict__ glist,
                                                  const int* __restrict__ gcount,
                                                  ushort_t* __restrict__ AOh,
                                                  ushort_t* __restrict__ AOl) {
    __shared__ char buf[2][16384];           // [K 8KB][Vt 8KB]
    __shared__ int jl[2][64];
    __shared__ ushort_t Ps[8 * 16 * 64];     // per-wave P^T, swizzled

    const int t = threadIdx.x, lane = t & 63, wave = t >> 6;
    const int q = lane & 15, g = lane >> 4;
    const int i0 = blockIdx.x * 128, h = blockIdx.y, b = blockIdx.z;
    const size_t headoff = ((size_t)(b * H_ + h)) * S_ * DK_;
    const int iq = i0 + wave * 16 + q;
    const int iqm = iq - WIN_;

    short8 qa[2];
    {
        const ushort_t* qrow = Qp + headoff + (size_t)iq * DK_;
        qa[0] = *(const short8*)(qrow + 8 * g);
        qa[1] = *(const short8*)(qrow + 32 + 8 * g);
    }

    f32x4 Oa[4];
    for (int n = 0; n < 4; ++n) Oa[n] = f32x4{0.f, 0.f, 0.f, 0.f};
    float m_st = -1e30f, l_st = 0.f;

    int jlo = i0 - WIN_;
    int jt_lo = (jlo < 0) ? 0 : (jlo >> 6);
    int jhi = i0 + 127 + WIN_; if (jhi > S_ - 1) jhi = S_ - 1;
    int jt_hi = jhi >> 6;
    int nband = jt_hi - jt_lo + 1;
    const int G = gcount[0];
    int nglob = (G + 63) >> 6; if (nglob > NGT) nglob = NGT;
    int nchunk = nband + nglob;

    const size_t bh = (size_t)(b * H_ + h);

    // hoisted LDS offsets (chunk-invariant)
    int koff[4][2], poffw[4], poffr[2];
    #pragma unroll
    for (int n = 0; n < 4; ++n) {
        int row = n * 16 + q;
        #pragma unroll
        for (int kt = 0; kt < 2; ++kt)
            koff[n][kt] = (row * 128 + g * 16 + kt * 64) ^ ((row & 7) << 4);
        poffw[n] = (q * 128 + n * 32 + g * 8) ^ ((q & 7) << 4);
    }
    #pragma unroll
    for (int kt = 0; kt < 2; ++kt)
        poffr[kt] = (q * 128 + g * 16 + kt * 64) ^ ((q & 7) << 4);

    auto stage = [&](int ch, int nb) {
        const char* img = (ch < nband)
            ? bandimg + (bh * 64 + (jt_lo + ch)) * 16384
            : globimg + (bh * NGT + (ch - nband)) * 16384;
        #pragma unroll
        for (int i = 0; i < 2; ++i) {
            int seg = wave * 2 + i;
            __builtin_amdgcn_global_load_lds(
                (const __attribute__((address_space(1))) void*)(img + seg * 1024 + lane * 16),
                (__attribute__((address_space(3))) void*)(buf[nb] + seg * 1024),
                16, 0, 0);
        }
        if (ch >= nband && t < 64) {
            int gi = (ch - nband) * 64 + t;
            jl[nb][t] = (gi < G) ? glist[gi] : -1;
        }
    };

    stage(0, 0);
    __syncthreads();

    int cur = 0;
    for (int ch = 0; ch < nchunk; ++ch) {
        if (ch + 1 < nchunk) stage(ch + 1, cur ^ 1);
        const bool isband = ch < nband;
        const int cbase = isband ? (jt_lo + ch) * 64 : 0;
        const char* Kb = buf[cur];
        const char* Vb = buf[cur] + 8192;

        // QK^T swapped: sc[n][r] = S[j = 16n+4g+r][q]  (log2 domain)
        f32x4 sc[4];
        for (int n = 0; n < 4; ++n) sc[n] = f32x4{0.f, 0.f, 0.f, 0.f};
        #pragma unroll
        for (int n = 0; n < 4; ++n)
            #pragma unroll
            for (int kt = 0; kt < 2; ++kt) {
                short8 ka = *(const short8*)(Kb + koff[n][kt]);
                sc[n] = __builtin_amdgcn_mfma_f32_16x16x32_bf16(ka, qa[kt], sc[n], 0, 0, 0);
            }

        // mask + lane-local max
        float pm = -1e30f;
        if (isband) {
            #pragma unroll
            for (int n = 0; n < 4; ++n) {
                int jb = cbase + n * 16 + 4 * g;
                #pragma unroll
                for (int r = 0; r < 4; ++r) {
                    bool inwin = (unsigned)(jb + r - iqm) <= 2 * WIN_;
                    float s = inwin ? sc[n][r] : -1e30f;
                    sc[n][r] = s;
                    pm = fmaxf(pm, s);
                }
            }
        } else {
            #pragma unroll
            for (int n = 0; n < 4; ++n) {
                int4 J = *(const int4*)(&jl[cur][n * 16 + g * 4]);
                int js[4] = {J.x, J.y, J.z, J.w};
                #pragma unroll
                for (int r = 0; r < 4; ++r) {
                    int jj = js[r];
                    bool inwin = (unsigned)(jj - iqm) <= 2 * WIN_;
                    bool allow = (jj >= 0) && !inwin;
                    float s = allow ? sc[n][r] : -1e30f;
                    sc[n][r] = s;
                    pm = fmaxf(pm, s);
                }
            }
        }
        pm = fmaxf(pm, __shfl_xor(pm, 16, 64));
        pm = fmaxf(pm, __shfl_xor(pm, 32, 64));

        bool skip = __all(pm <= m_st);   // exact: fac would be 1
        float fac = 1.0f;
        if (!skip) {
            float mn = fmaxf(m_st, pm);
            fac = exp2f(m_st - mn);
            m_st = mn;
        }
        float rs = 0.f;
        #pragma unroll
        for (int n = 0; n < 4; ++n)
            #pragma unroll
            for (int r = 0; r < 4; ++r) {
                float p = exp2f(sc[n][r] - m_st);
                sc[n][r] = p;
                rs += p;
            }
        rs += __shfl_xor(rs, 16, 64);
        rs += __shfl_xor(rs, 32, 64);
        l_st = skip ? (l_st + rs) : (l_st * fac + rs);

        // P^T -> wave-private LDS via v_cvt_pk_bf16_f32 (b64 writes)
        ushort_t* Pw = Ps + wave * 1024;
        #pragma unroll
        for (int n = 0; n < 4; ++n) {
            unsigned pk0 = cvt_pk_bf16(sc[n][0], sc[n][1]);
            unsigned pk1 = cvt_pk_bf16(sc[n][2], sc[n][3]);
            *(unsigned long long*)((char*)Pw + poffw[n]) =
                ((unsigned long long)pk1 << 32) | pk0;
        }

        if (!skip) {
            #pragma unroll
            for (int n = 0; n < 4; ++n)
                #pragma unroll
                for (int r = 0; r < 4; ++r) Oa[n][r] *= fac;
        }

        short8 pa[2];
        #pragma unroll
        for (int kt = 0; kt < 2; ++kt)
            pa[kt] = *(const short8*)((char*)Pw + poffr[kt]);
        #pragma unroll
        for (int n = 0; n < 4; ++n)
            #pragma unroll
            for (int kt = 0; kt < 2; ++kt) {
                short8 va = *(const short8*)(Vb + koff[n][kt]);
                Oa[n] = __builtin_amdgcn_mfma_f32_16x16x32_bf16(va, pa[kt], Oa[n], 0, 0, 0);
            }
        __syncthreads();
        cur ^= 1;
    }

    // epilogue: normalize, write hi/lo bf16 AO
    float inv = 1.0f / l_st;
    #pragma unroll
    for (int n = 0; n < 4; ++n) {
        us4 ph, pl;
        #pragma unroll
        for (int r = 0; r < 4; ++r) {
            float v = Oa[n][r] * inv;
            unsigned short hb = f2bf(v);
            ph[r] = hb;
            pl[r] = f2bf(v - bf2f(hb));
        }
        size_t base = ((size_t)b * S_ + iq) * D_ + h * DK_ + (n * 16 + g * 4);
        *(us4*)(AOh + base) = ph;
        *(us4*)(AOl + base) = pl;
    }
}

// ---------------- launch ----------------------------------------------------
extern "C" void kernel_launch(void* const* d_in, const int* in_sizes, int n_in,
                              void* d_out, int out_size, void* d_ws, size_t ws_size,
                              hipStream_t stream) {
    const float* x      = (const float*)d_in[0];
    const int*   opcode = (const int*)d_in[1];
    const float* Wq = (const float*)d_in[2];
    const float* bq = (const float*)d_in[3];
    const float* Wk = (const float*)d_in[4];
    const float* bk = (const float*)d_in[5];
    const float* Wv = (const float*)d_in[6];
    const float* bv = (const float*)d_in[7];
    const float* Wo = (const float*)d_in[8];
    const float* bo = (const float*)d_in[9];
    float* out = (float*)d_out;

    char* ws = (char*)d_ws;
    const size_t bsd = (size_t)B_ * S_ * D_;
    const size_t bf_bytes = bsd * sizeof(ushort_t);                 // 8.39 MB
    const size_t w_bytes  = (size_t)D_ * D_ * sizeof(ushort_t);     // 0.52 MB

    ushort_t* qb  = (ushort_t*)(ws);
    ushort_t* xh  = (ushort_t*)(ws + bf_bytes);
    ushort_t* aol = (ushort_t*)(ws + 2 * bf_bytes);
    ushort_t* aoh = xh;                         // reuse after projections
    char* wbase = ws + 3 * bf_bytes;
    ushort_t* whb = (ushort_t*)wbase;           // 4 weights hi, contiguous
    ushort_t* wol = (ushort_t*)(wbase + 4 * w_bytes);
    char* bandimg = wbase + 5 * w_bytes;                         // 16*64*16KB
    char* globimg = bandimg + (size_t)16 * 64 * 16384;           // 16*NGT*16KB
    int* glist  = (int*)(globimg + (size_t)16 * NGT * 16384);
    int* gcount = glist + S_;

    prep_all<<<5121, 256, 0, stream>>>(x, Wq, Wk, Wv, Wo, opcode,
                                       xh, whb, wol, glist, gcount);

    gemm_qkv<<<dim3(D_ / 128, (B_ * S_) / 128, 3), 256, 0, stream>>>(
        xh, whb, bq, bk, bv, qb, bandimg);

    prep_glob<<<dim3(NGT, H_, B_), 256, 0, stream>>>(bandimg, globimg, glist, gcount);

    attn_mfma4<<<dim3(S_ / 128, H_, B_), 512, 0, stream>>>(
        qb, bandimg, globimg, glist, gcount, aoh, aol);

    gemm_fin<<<dim3(D_ / 128, (B_ * S_) / 128), 256, 0, stream>>>(
        whb + 3 * (size_t)D_ * D_, wol, aoh, aol, bo, out);
}

// Round 7
// 195.983 us; speedup vs baseline: 9.0355x; 1.0443x over previous
//
#include <hip/hip_runtime.h>
#include <hip/hip_bf16.h>
#include <math.h>

#define B_ 2
#define S_ 4096
#define D_ 512
#define H_ 8
#define DK_ 64
#define WIN_ 50
#define NGT 32   // max global chunks (2048 cols; E[G]~780)
#define QSCALE 0.18033688011112042f   // 0.125 * log2(e): softmax in log2 domain

typedef __attribute__((ext_vector_type(8))) short short8;   // 8 bf16 bit-patterns
typedef __attribute__((ext_vector_type(4))) float f32x4;
typedef __attribute__((ext_vector_type(4))) unsigned short us4;
typedef unsigned short ushort_t;

__device__ __forceinline__ unsigned short f2bf(float f) {
    unsigned u = __builtin_bit_cast(unsigned, f);
    u += 0x7FFF + ((u >> 16) & 1);   // RNE
    return (unsigned short)(u >> 16);
}
__device__ __forceinline__ float bf2f(unsigned short h) {
    return __builtin_bit_cast(float, ((unsigned)h) << 16);
}
__device__ __forceinline__ unsigned cvt_pk_bf16(float lo, float hi) {
    unsigned r;
    asm("v_cvt_pk_bf16_f32 %0, %1, %2" : "=v"(r) : "v"(lo), "v"(hi));
    return r;
}
// raw v_exp_f32 (2^x). s_nop covers the VALU-trans consumer hazard.
__device__ __forceinline__ float v_exp2(float x) {
    float r;
    asm("v_exp_f32 %0, %1\n\ts_nop 0" : "=v"(r) : "v"(x));
    return r;
}

// ---------------- fused prep: split x (hi), split W (hi; lo for Wo), glist --
__global__ __launch_bounds__(256) void prep_all(const float* __restrict__ x,
                                                const float* __restrict__ W0,
                                                const float* __restrict__ W1,
                                                const float* __restrict__ W2,
                                                const float* __restrict__ W3,
                                                const int* __restrict__ opcode,
                                                ushort_t* __restrict__ xh,
                                                ushort_t* __restrict__ whb,
                                                ushort_t* __restrict__ wol,
                                                int* __restrict__ glist,
                                                int* __restrict__ gcount) {
    const int bid = blockIdx.x;
    const int t = threadIdx.x;
    if (bid < 4096) {                       // x -> bf16 hi only
        int i = bid * 256 + t;
        f32x4 v = ((const f32x4*)x)[i];
        us4 hv;
        for (int e = 0; e < 4; ++e) hv[e] = f2bf(v[e]);
        ((us4*)xh)[i] = hv;
    } else if (bid < 5120) {                // weights
        int b2 = bid - 4096;
        int wz = b2 >> 8, inner = b2 & 255;
        const float* src = (wz == 0) ? W0 : (wz == 1) ? W1 : (wz == 2) ? W2 : W3;
        int i = inner * 256 + t;
        f32x4 v = ((const f32x4*)src)[i];
        us4 hv, lv;
        for (int e = 0; e < 4; ++e) {
            unsigned short hb = f2bf(v[e]);
            hv[e] = hb;
            lv[e] = f2bf(v[e] - bf2f(hb));
        }
        ((us4*)(whb + (size_t)wz * D_ * D_))[i] = hv;
        if (wz == 3) ((us4*)wol)[i] = lv;
    } else {                                // glist scan (sorted compact)
        __shared__ int cnts[256];
        unsigned fl = 0; int c = 0;
        for (int k = 0; k < 16; ++k) {
            int col = t * 16 + k;
            int flag = (opcode[col] == 0) | (opcode[S_ + col] == 0);
            fl |= (unsigned)flag << k; c += flag;
        }
        cnts[t] = c;
        __syncthreads();
        for (int off = 1; off < 256; off <<= 1) {
            int v = cnts[t];
            int a = (t >= off) ? cnts[t - off] : 0;
            __syncthreads();
            cnts[t] = v + a;
            __syncthreads();
        }
        int base = cnts[t] - c;
        for (int k = 0; k < 16; ++k)
            if ((fl >> k) & 1) glist[base++] = t * 16 + k;
        int G = cnts[255];
        if (t == 255) gcount[0] = G;
        // pad tail with -1 so attention can load int4 unguarded
        for (int k = 0; k < 8; ++k) {
            int idx = G + t + k * 256;
            if (idx < S_) glist[idx] = -1;
        }
    }
}

// ---------------- pure-bf16 GEMM core -------------------------------------
// 128x128 tile, BK=32, 4 waves, double-buffered global_load_lds.
// LDS per buffer (ushort idx): tile(A0/B1)*4096 + kg*1024 + row*8
__device__ __forceinline__ void gemm_core1(const ushort_t* __restrict__ A,
                                           const ushort_t* __restrict__ Bw,
                                           ushort_t (&LDS)[2][8192],
                                           int m0, int n0, int t,
                                           f32x4 (&acc)[4][4]) {
    const int lane = t & 63, wave = t >> 6;
    const int lrow = lane & 15, lkg = lane >> 4;
    const int wr = wave >> 1, wc = wave & 1;
    const ushort_t* srcs[2] = {A, Bw};
    const int row0[2] = {m0, n0};

    auto stage = [&](int buf, int k0) {
        #pragma unroll
        for (int it = 0; it < 4; ++it) {
            int c = it * 4 + wave;
            int tile = c >> 3;
            int kg = (c >> 1) & 3;
            int r = ((c & 1) << 6) | lane;
            const ushort_t* g = srcs[tile] + (size_t)(row0[tile] + r) * 512 + k0 + kg * 8;
            __builtin_amdgcn_global_load_lds(
                (const __attribute__((address_space(1))) void*)g,
                (__attribute__((address_space(3))) void*)(&LDS[buf][c * 512]),
                16, 0, 0);
        }
    };

    stage(0, 0);
    __syncthreads();

    const int aoff = lkg * 1024 + (wr * 64 + lrow) * 8;
    const int boff = 4096 + lkg * 1024 + (wc * 64 + lrow) * 8;
    int cur = 0;
    for (int ks = 0; ks < 16; ++ks) {
        if (ks < 15) stage(cur ^ 1, (ks + 1) * 32);
        const ushort_t* Lb = LDS[cur];
        short8 ah[4], bh[4];
        #pragma unroll
        for (int m = 0; m < 4; ++m) ah[m] = *(const short8*)(Lb + aoff + m * 128);
        #pragma unroll
        for (int n = 0; n < 4; ++n) bh[n] = *(const short8*)(Lb + boff + n * 128);
        #pragma unroll
        for (int m = 0; m < 4; ++m)
            #pragma unroll
            for (int n = 0; n < 4; ++n)
                acc[m][n] = __builtin_amdgcn_mfma_f32_16x16x32_bf16(ah[m], bh[n], acc[m][n], 0, 0, 0);
        __syncthreads();
        cur ^= 1;
    }
}

// ---------------- split-3 GEMM core (final projection, swapped) -------------
__device__ __forceinline__ void gemm_core3(const ushort_t* __restrict__ Ah,
                                           const ushort_t* __restrict__ Al,
                                           const ushort_t* __restrict__ Bh,
                                           const ushort_t* __restrict__ Bl,
                                           ushort_t (&LDS)[2][16384],
                                           int m0, int n0, int t,
                                           f32x4 (&acc)[4][4]) {
    const int lane = t & 63, wave = t >> 6;
    const int lrow = lane & 15, lkg = lane >> 4;
    const int wr = wave >> 1, wc = wave & 1;
    const ushort_t* srcs[4] = {Ah, Al, Bh, Bl};
    const int row0[4] = {m0, m0, n0, n0};

    auto stage = [&](int buf, int k0) {
        #pragma unroll
        for (int it = 0; it < 8; ++it) {
            int c = it * 4 + wave;
            int tile = c >> 3;
            int kg = (c >> 1) & 3;
            int r = ((c & 1) << 6) | lane;
            const ushort_t* g = srcs[tile] + (size_t)(row0[tile] + r) * 512 + k0 + kg * 8;
            __builtin_amdgcn_global_load_lds(
                (const __attribute__((address_space(1))) void*)g,
                (__attribute__((address_space(3))) void*)(&LDS[buf][c * 512]),
                16, 0, 0);
        }
    };

    stage(0, 0);
    __syncthreads();

    const int aoff = lkg * 1024 + (wr * 64 + lrow) * 8;
    const int boff = 2 * 4096 + lkg * 1024 + (wc * 64 + lrow) * 8;
    int cur = 0;
    for (int ks = 0; ks < 16; ++ks) {
        if (ks < 15) stage(cur ^ 1, (ks + 1) * 32);
        const ushort_t* Lb = LDS[cur];
        short8 ah[4], al[4], bh[4], bl[4];
        #pragma unroll
        for (int m = 0; m < 4; ++m) {
            ah[m] = *(const short8*)(Lb + aoff + m * 128);
            al[m] = *(const short8*)(Lb + 4096 + aoff + m * 128);
        }
        #pragma unroll
        for (int n = 0; n < 4; ++n) {
            bh[n] = *(const short8*)(Lb + boff + n * 128);
            bl[n] = *(const short8*)(Lb + 4096 + boff + n * 128);
        }
        #pragma unroll
        for (int m = 0; m < 4; ++m)
            #pragma unroll
            for (int n = 0; n < 4; ++n) {
                acc[m][n] = __builtin_amdgcn_mfma_f32_16x16x32_bf16(ah[m], bh[n], acc[m][n], 0, 0, 0);
                acc[m][n] = __builtin_amdgcn_mfma_f32_16x16x32_bf16(al[m], bh[n], acc[m][n], 0, 0, 0);
                acc[m][n] = __builtin_amdgcn_mfma_f32_16x16x32_bf16(ah[m], bl[n], acc[m][n], 0, 0, 0);
            }
        __syncthreads();
        cur ^= 1;
    }
}

// merged Q/K/V projection: z=0 Q (swapped), z=1 K (swapped), z=2 V (normal)
__global__ __launch_bounds__(256) void gemm_qkv(const ushort_t* __restrict__ xh,
                                                const ushort_t* __restrict__ whb,
                                                const float* __restrict__ bq,
                                                const float* __restrict__ bk,
                                                const float* __restrict__ bv,
                                                ushort_t* __restrict__ qb,
                                                char* __restrict__ bandimg) {
    __shared__ ushort_t LDS[2][8192];
    const int z = blockIdx.z;
    const int t = threadIdx.x;
    const ushort_t* Wz = whb + (size_t)z * D_ * D_;
    const int lane = t & 63, wave = t >> 6;
    const int lrow = lane & 15, lkg = lane >> 4;
    const int wr = wave >> 1, wc = wave & 1;

    f32x4 acc[4][4];
    for (int m = 0; m < 4; ++m)
        for (int n = 0; n < 4; ++n)
            acc[m][n] = f32x4{0.f, 0.f, 0.f, 0.f};

    if (z == 2) {
        // V: A = x rows (s), B = Wv rows (d)
        const int m0 = blockIdx.y * 128, n0 = blockIdx.x * 128;
        gemm_core1(xh, Wz, LDS, m0, n0, t, acc);
        for (int m = 0; m < 4; ++m) {
            int s_base = m0 + wr * 64 + m * 16 + lkg * 4;
            int bb = s_base >> 12, s0 = s_base & (S_ - 1);
            int jt = s0 >> 6, jr0 = s0 & 63;
            for (int n = 0; n < 4; ++n) {
                int col = n0 + wc * 64 + n * 16 + lrow;
                float bs = bv[col];
                int hh = col >> 6, dk = col & 63;
                us4 pk;
                for (int r = 0; r < 4; ++r) pk[r] = f2bf(acc[m][n][r] + bs);
                char* img = bandimg + (((size_t)(bb * H_ + hh)) * 64 + jt) * 16384 + 8192;
                *(us4*)(img + ((dk * 128 + jr0 * 2) ^ ((dk & 7) << 4))) = pk;
            }
        }
    } else {
        // Q/K swapped: A = W rows (d), B = x rows (s)
        const int m0 = blockIdx.x * 128, n0 = blockIdx.y * 128;
        gemm_core1(Wz, xh, LDS, m0, n0, t, acc);
        const float* bias = (z == 0) ? bq : bk;
        for (int m = 0; m < 4; ++m) {
            int d_base = m0 + wr * 64 + m * 16 + lkg * 4;
            f32x4 b4 = *(const f32x4*)(bias + d_base);
            int hh = d_base >> 6, dkb = d_base & 63;
            for (int n = 0; n < 4; ++n) {
                int s = n0 + wc * 64 + n * 16 + lrow;
                int bb = s >> 12, sl = s & (S_ - 1);
                us4 pk;
                if (z == 0) {
                    for (int r = 0; r < 4; ++r) pk[r] = f2bf((acc[m][n][r] + b4[r]) * QSCALE);
                    *(us4*)(qb + (((size_t)(bb * H_ + hh) * S_) + sl) * DK_ + dkb) = pk;
                } else {
                    for (int r = 0; r < 4; ++r) pk[r] = f2bf(acc[m][n][r] + b4[r]);
                    int jt = sl >> 6, jr = sl & 63;
                    char* img = bandimg + (((size_t)(bb * H_ + hh)) * 64 + jt) * 16384;
                    *(us4*)(img + ((jr * 128 + dkb * 2) ^ ((jr & 7) << 4))) = pk;
                }
            }
        }
    }
}

// final projection (swapped, split-3): out[s][d] = ao @ Wo^T + bo, fp32
__global__ __launch_bounds__(256) void gemm_fin(const ushort_t* __restrict__ Woh,
                                                const ushort_t* __restrict__ Wol,
                                                const ushort_t* __restrict__ aoh,
                                                const ushort_t* __restrict__ aol,
                                                const float* __restrict__ bias,
                                                float* __restrict__ outp) {
    __shared__ ushort_t LDS[2][16384];
    const int t = threadIdx.x;
    const int lane = t & 63, wave = t >> 6;
    const int lrow = lane & 15, lkg = lane >> 4;
    const int wr = wave >> 1, wc = wave & 1;
    const int m0 = blockIdx.x * 128, n0 = blockIdx.y * 128;

    f32x4 acc[4][4];
    for (int m = 0; m < 4; ++m)
        for (int n = 0; n < 4; ++n)
            acc[m][n] = f32x4{0.f, 0.f, 0.f, 0.f};
    gemm_core3(Woh, Wol, aoh, aol, LDS, m0, n0, t, acc);

    for (int m = 0; m < 4; ++m) {
        int d_base = m0 + wr * 64 + m * 16 + lkg * 4;
        f32x4 b4 = *(const f32x4*)(bias + d_base);
        for (int n = 0; n < 4; ++n) {
            int s = n0 + wc * 64 + n * 16 + lrow;
            f32x4 o;
            for (int r = 0; r < 4; ++r) o[r] = acc[m][n][r] + b4[r];
            *(f32x4*)(outp + (size_t)s * D_ + d_base) = o;
        }
    }
}

// ---------------- gather global-column chunks into images -------------------
__global__ __launch_bounds__(256) void prep_glob(const char* __restrict__ bandimg,
                                                 char* __restrict__ globimg,
                                                 const int* __restrict__ glist,
                                                 const int* __restrict__ gcount) {
    int G = gcount[0];
    int gc = blockIdx.x;
    if (gc * 64 >= G) return;
    int h = blockIdx.y, b = blockIdx.z;
    int t = threadIdx.x;
    __shared__ int jl[64];
    if (t < 64) { int gi = gc * 64 + t; jl[t] = (gi < G) ? glist[gi] : -1; }
    __syncthreads();
    const size_t bh = (size_t)(b * H_ + h);
    char* dst = globimg + (bh * NGT + gc) * 16384;
    {
        int c = t >> 2, q = t & 3;
        int jj = jl[c];
        #pragma unroll
        for (int p = 0; p < 2; ++p) {
            int o_dst = c * 128 + q * 32 + p * 16;
            short8 val;
            if (jj >= 0) {
                int jr = jj & 63, jt = jj >> 6;
                const char* src = bandimg + (bh * 64 + jt) * 16384;
                val = *(const short8*)(src + ((jr * 128 + q * 32 + p * 16) ^ ((jr & 7) << 4)));
            } else {
                for (int e = 0; e < 8; ++e) val[e] = 0;
            }
            *(short8*)(dst + (o_dst ^ ((c & 7) << 4))) = val;
        }
    }
    {
        int d = t >> 2, qq = t & 3;
        short8 v0, v1;
        #pragma unroll 16
        for (int i = 0; i < 16; ++i) {
            int c = qq * 16 + i;
            int jj = jl[c];
            ushort_t val = 0;
            if (jj >= 0) {
                int jr = jj & 63, jt = jj >> 6;
                const char* src = bandimg + (bh * 64 + jt) * 16384 + 8192;
                val = *(const ushort_t*)(src + ((d * 128 + jr * 2) ^ ((d & 7) << 4)));
            }
            if (i < 8) v0[i] = val; else v1[i - 8] = val;
        }
        int o = d * 128 + qq * 32;
        *(short8*)(dst + 8192 + (o ^ ((d & 7) << 4))) = v0;
        *(short8*)(dst + 8192 + ((o + 16) ^ ((d & 7) << 4))) = v1;
    }
}

// ---------------- sparse flash attention: needmask + raw v_exp + XCD swz ----
// grid: 1-D 512 blocks; bh = bid & 15 keeps each (b,h)'s images XCD-local.
__global__ __launch_bounds__(512) void attn_mfma5(const ushort_t* __restrict__ Qp,
                                                  const char* __restrict__ bandimg,
                                                  const char* __restrict__ globimg,
                                                  const int* __restrict__ glist,
                                                  const int* __restrict__ gcount,
                                                  ushort_t* __restrict__ AOh,
                                                  ushort_t* __restrict__ AOl) {
    __shared__ char buf[2][16384];           // [K 8KB][Vt 8KB]
    __shared__ ushort_t Ps[8 * 16 * 64];     // per-wave P^T, swizzled

    const int t = threadIdx.x, lane = t & 63, wave = t >> 6;
    const int q = lane & 15, g = lane >> 4;
    const int bid = blockIdx.x;
    const int bh_lin = bid & 15;              // XCD-local (b,h)
    const int b = bh_lin >> 3, h = bh_lin & 7;
    const int i0 = (bid >> 4) * 128;
    const size_t headoff = ((size_t)(b * H_ + h)) * S_ * DK_;
    const int iq = i0 + wave * 16 + q;
    const int iqm = iq - WIN_;

    short8 qa[2];
    {
        const ushort_t* qrow = Qp + headoff + (size_t)iq * DK_;
        qa[0] = *(const short8*)(qrow + 8 * g);
        qa[1] = *(const short8*)(qrow + 32 + 8 * g);
    }

    f32x4 Oa[4];
    for (int n = 0; n < 4; ++n) Oa[n] = f32x4{0.f, 0.f, 0.f, 0.f};
    float m_st = -1e30f, l_st = 0.f;

    int jlo = i0 - WIN_;
    int jt_lo = (jlo < 0) ? 0 : (jlo >> 6);
    int jhi = i0 + 127 + WIN_; if (jhi > S_ - 1) jhi = S_ - 1;
    int jt_hi = jhi >> 6;
    int nband = jt_hi - jt_lo + 1;
    const int G = gcount[0];
    int nglob = (G + 63) >> 6; if (nglob > NGT) nglob = NGT;
    int nchunk = nband + nglob;

    const size_t bh = (size_t)(b * H_ + h);

    // which glob chunks need the mask? (sorted glist -> range test; partial tail)
    unsigned needmask = 0;
    {
        int wmin = i0 - WIN_, wmax = i0 + 127 + WIN_;
        for (int gc = 0; gc < nglob; ++gc) {
            int lo = glist[gc * 64];
            int hidx = (gc * 64 + 63 < G) ? (gc * 64 + 63) : (G - 1);
            int hi = glist[hidx];
            bool nm = (lo <= wmax && hi >= wmin) || (gc == nglob - 1 && (G & 63));
            needmask |= (unsigned)nm << gc;
        }
    }

    // hoisted LDS offsets (chunk-invariant)
    int koff[4][2], poffw[4], poffr[2];
    #pragma unroll
    for (int n = 0; n < 4; ++n) {
        int row = n * 16 + q;
        #pragma unroll
        for (int kt = 0; kt < 2; ++kt)
            koff[n][kt] = (row * 128 + g * 16 + kt * 64) ^ ((row & 7) << 4);
        poffw[n] = (q * 128 + n * 32 + g * 8) ^ ((q & 7) << 4);
    }
    #pragma unroll
    for (int kt = 0; kt < 2; ++kt)
        poffr[kt] = (q * 128 + g * 16 + kt * 64) ^ ((q & 7) << 4);

    const char* band_base = bandimg + (bh * 64 + jt_lo) * 16384;
    const char* glob_base = globimg + (bh * NGT) * 16384;

    auto stage = [&](int ch, int nb) {
        const char* img = (ch < nband) ? (band_base + (size_t)ch * 16384)
                                       : (glob_base + (size_t)(ch - nband) * 16384);
        #pragma unroll
        for (int i = 0; i < 2; ++i) {
            int seg = wave * 2 + i;
            __builtin_amdgcn_global_load_lds(
                (const __attribute__((address_space(1))) void*)(img + seg * 1024 + lane * 16),
                (__attribute__((address_space(3))) void*)(buf[nb] + seg * 1024),
                16, 0, 0);
        }
    };

    stage(0, 0);
    __syncthreads();

    int cur = 0;
    for (int ch = 0; ch < nchunk; ++ch) {
        if (ch + 1 < nchunk) stage(ch + 1, cur ^ 1);
        const bool isband = ch < nband;
        const int cbase = isband ? (jt_lo + ch) * 64 : 0;
        const int gbase = (ch - nband) * 64;
        const char* Kb = buf[cur];
        const char* Vb = buf[cur] + 8192;

        // QK^T swapped: sc[n][r] = S[j = 16n+4g+r][q]  (log2 domain)
        f32x4 sc[4];
        for (int n = 0; n < 4; ++n) sc[n] = f32x4{0.f, 0.f, 0.f, 0.f};
        #pragma unroll
        for (int n = 0; n < 4; ++n)
            #pragma unroll
            for (int kt = 0; kt < 2; ++kt) {
                short8 ka = *(const short8*)(Kb + koff[n][kt]);
                sc[n] = __builtin_amdgcn_mfma_f32_16x16x32_bf16(ka, qa[kt], sc[n], 0, 0, 0);
            }

        // mask (only where needed) + lane-local max
        float pm;
        bool nm = isband || ((needmask >> (ch - nband)) & 1);
        if (nm) {
            pm = -1e30f;
            if (isband) {
                #pragma unroll
                for (int n = 0; n < 4; ++n) {
                    int jb = cbase + n * 16 + 4 * g;
                    #pragma unroll
                    for (int r = 0; r < 4; ++r) {
                        bool inwin = (unsigned)(jb + r - iqm) <= 2 * WIN_;
                        float s = inwin ? sc[n][r] : -1e30f;
                        sc[n][r] = s;
                        pm = fmaxf(pm, s);
                    }
                }
            } else {
                #pragma unroll
                for (int n = 0; n < 4; ++n) {
                    int4 J = *(const int4*)(glist + gbase + n * 16 + g * 4);
                    int js[4] = {J.x, J.y, J.z, J.w};
                    #pragma unroll
                    for (int r = 0; r < 4; ++r) {
                        int jj = js[r];
                        bool inwin = (unsigned)(jj - iqm) <= 2 * WIN_;
                        bool allow = (jj >= 0) && !inwin;
                        float s = allow ? sc[n][r] : -1e30f;
                        sc[n][r] = s;
                        pm = fmaxf(pm, s);
                    }
                }
            }
        } else {
            // mask-free: pure max tree (max3-friendly)
            float a0 = fmaxf(fmaxf(sc[0][0], sc[0][1]), fmaxf(sc[0][2], sc[0][3]));
            float a1 = fmaxf(fmaxf(sc[1][0], sc[1][1]), fmaxf(sc[1][2], sc[1][3]));
            float a2 = fmaxf(fmaxf(sc[2][0], sc[2][1]), fmaxf(sc[2][2], sc[2][3]));
            float a3 = fmaxf(fmaxf(sc[3][0], sc[3][1]), fmaxf(sc[3][2], sc[3][3]));
            pm = fmaxf(fmaxf(a0, a1), fmaxf(a2, a3));
        }
        pm = fmaxf(pm, __shfl_xor(pm, 16, 64));
        pm = fmaxf(pm, __shfl_xor(pm, 32, 64));

        bool skip = __all(pm <= m_st);   // exact: fac would be 1
        float fac = 1.0f;
        if (!skip) {
            float mn = fmaxf(m_st, pm);
            fac = v_exp2(m_st - mn);
            m_st = mn;
        }
        float rs = 0.f;
        #pragma unroll
        for (int n = 0; n < 4; ++n)
            #pragma unroll
            for (int r = 0; r < 4; ++r) {
                float p = v_exp2(sc[n][r] - m_st);
                sc[n][r] = p;
                rs += p;
            }
        rs += __shfl_xor(rs, 16, 64);
        rs += __shfl_xor(rs, 32, 64);
        l_st = skip ? (l_st + rs) : (l_st * fac + rs);

        // P^T -> wave-private LDS via v_cvt_pk_bf16_f32 (b64 writes)
        ushort_t* Pw = Ps + wave * 1024;
        #pragma unroll
        for (int n = 0; n < 4; ++n) {
            unsigned pk0 = cvt_pk_bf16(sc[n][0], sc[n][1]);
            unsigned pk1 = cvt_pk_bf16(sc[n][2], sc[n][3]);
            *(unsigned long long*)((char*)Pw + poffw[n]) =
                ((unsigned long long)pk1 << 32) | pk0;
        }

        if (!skip) {
            #pragma unroll
            for (int n = 0; n < 4; ++n)
                #pragma unroll
                for (int r = 0; r < 4; ++r) Oa[n][r] *= fac;
        }

        short8 pa[2];
        #pragma unroll
        for (int kt = 0; kt < 2; ++kt)
            pa[kt] = *(const short8*)((char*)Pw + poffr[kt]);
        #pragma unroll
        for (int n = 0; n < 4; ++n)
            #pragma unroll
            for (int kt = 0; kt < 2; ++kt) {
                short8 va = *(const short8*)(Vb + koff[n][kt]);
                Oa[n] = __builtin_amdgcn_mfma_f32_16x16x32_bf16(va, pa[kt], Oa[n], 0, 0, 0);
            }
        __syncthreads();
        cur ^= 1;
    }

    // epilogue: normalize, write hi/lo bf16 AO
    float inv = 1.0f / l_st;
    #pragma unroll
    for (int n = 0; n < 4; ++n) {
        us4 ph, pl;
        #pragma unroll
        for (int r = 0; r < 4; ++r) {
            float v = Oa[n][r] * inv;
            unsigned short hb = f2bf(v);
            ph[r] = hb;
            pl[r] = f2bf(v - bf2f(hb));
        }
        size_t base = ((size_t)b * S_ + iq) * D_ + h * DK_ + (n * 16 + g * 4);
        *(us4*)(AOh + base) = ph;
        *(us4*)(AOl + base) = pl;
    }
}

// ---------------- launch ----------------------------------------------------
extern "C" void kernel_launch(void* const* d_in, const int* in_sizes, int n_in,
                              void* d_out, int out_size, void* d_ws, size_t ws_size,
                              hipStream_t stream) {
    const float* x      = (const float*)d_in[0];
    const int*   opcode = (const int*)d_in[1];
    const float* Wq = (const float*)d_in[2];
    const float* bq = (const float*)d_in[3];
    const float* Wk = (const float*)d_in[4];
    const float* bk = (const float*)d_in[5];
    const float* Wv = (const float*)d_in[6];
    const float* bv = (const float*)d_in[7];
    const float* Wo = (const float*)d_in[8];
    const float* bo = (const float*)d_in[9];
    float* out = (float*)d_out;

    char* ws = (char*)d_ws;
    const size_t bsd = (size_t)B_ * S_ * D_;
    const size_t bf_bytes = bsd * sizeof(ushort_t);                 // 8.39 MB
    const size_t w_bytes  = (size_t)D_ * D_ * sizeof(ushort_t);     // 0.52 MB

    ushort_t* qb  = (ushort_t*)(ws);
    ushort_t* xh  = (ushort_t*)(ws + bf_bytes);
    ushort_t* aol = (ushort_t*)(ws + 2 * bf_bytes);
    ushort_t* aoh = xh;                         // reuse after projections
    char* wbase = ws + 3 * bf_bytes;
    ushort_t* whb = (ushort_t*)wbase;           // 4 weights hi, contiguous
    ushort_t* wol = (ushort_t*)(wbase + 4 * w_bytes);
    char* bandimg = wbase + 5 * w_bytes;                         // 16*64*16KB
    char* globimg = bandimg + (size_t)16 * 64 * 16384;           // 16*NGT*16KB
    int* glist  = (int*)(globimg + (size_t)16 * NGT * 16384);
    int* gcount = glist + S_;

    prep_all<<<5121, 256, 0, stream>>>(x, Wq, Wk, Wv, Wo, opcode,
                                       xh, whb, wol, glist, gcount);

    gemm_qkv<<<dim3(D_ / 128, (B_ * S_) / 128, 3), 256, 0, stream>>>(
        xh, whb, bq, bk, bv, qb, bandimg);

    prep_glob<<<dim3(NGT, H_, B_), 256, 0, stream>>>(bandimg, globimg, glist, gcount);

    attn_mfma5<<<dim3(512), 512, 0, stream>>>(
        qb, bandimg, globimg, glist, gcount, aoh, aol);

    gemm_fin<<<dim3(D_ / 128, (B_ * S_) / 128), 256, 0, stream>>>(
        whb + 3 * (size_t)D_ * D_, wol, aoh, aol, bo, out);
}

// Round 9
// 188.633 us; speedup vs baseline: 9.3875x; 1.0390x over previous
//
#include <hip/hip_runtime.h>
#include <hip/hip_bf16.h>
#include <math.h>

#define B_ 2
#define S_ 4096
#define D_ 512
#define H_ 8
#define DK_ 64
#define WIN_ 50
#define NGT 32   // max global chunks (2048 cols; E[G]~780)
#define QSCALE 0.18033688011112042f   // 0.125 * log2(e): softmax in log2 domain

typedef __attribute__((ext_vector_type(8))) _Float16 half8;  // MFMA A/B frag
typedef __attribute__((ext_vector_type(4))) float f32x4;
typedef __attribute__((ext_vector_type(4))) unsigned short us4;
typedef unsigned short ushort_t;

__device__ __forceinline__ unsigned short f2h(float f) {
    _Float16 h = (_Float16)f;                    // v_cvt_f16_f32 (RNE)
    return __builtin_bit_cast(unsigned short, h);
}
// packed f32->f16 convert: lo -> low16, hi -> high16 (v_cvt_pkrtz_f16_f32)
__device__ __forceinline__ unsigned cvt_pk_f16(float lo, float hi) {
    unsigned r;
    asm("v_cvt_pkrtz_f16_f32 %0, %1, %2" : "=v"(r) : "v"(lo), "v"(hi));
    return r;
}
// raw v_exp_f32 (2^x). s_nop covers the VALU-trans consumer hazard.
__device__ __forceinline__ float v_exp2(float x) {
    float r;
    asm("v_exp_f32 %0, %1\n\ts_nop 0" : "=v"(r) : "v"(x));
    return r;
}

// ---------------- fused prep: x->fp16, W->fp16, glist -----------------------
__global__ __launch_bounds__(256) void prep_all(const float* __restrict__ x,
                                                const float* __restrict__ W0,
                                                const float* __restrict__ W1,
                                                const float* __restrict__ W2,
                                                const float* __restrict__ W3,
                                                const int* __restrict__ opcode,
                                                ushort_t* __restrict__ xh,
                                                ushort_t* __restrict__ whb,
                                                int* __restrict__ glist,
                                                int* __restrict__ gcount) {
    const int bid = blockIdx.x;
    const int t = threadIdx.x;
    if (bid < 4096) {                       // x -> fp16
        int i = bid * 256 + t;
        f32x4 v = ((const f32x4*)x)[i];
        us4 hv;
        for (int e = 0; e < 4; ++e) hv[e] = f2h(v[e]);
        ((us4*)xh)[i] = hv;
    } else if (bid < 5120) {                // weights -> fp16
        int b2 = bid - 4096;
        int wz = b2 >> 8, inner = b2 & 255;
        const float* src = (wz == 0) ? W0 : (wz == 1) ? W1 : (wz == 2) ? W2 : W3;
        int i = inner * 256 + t;
        f32x4 v = ((const f32x4*)src)[i];
        us4 hv;
        for (int e = 0; e < 4; ++e) hv[e] = f2h(v[e]);
        ((us4*)(whb + (size_t)wz * D_ * D_))[i] = hv;
    } else {                                // glist scan (sorted compact)
        __shared__ int cnts[256];
        unsigned fl = 0; int c = 0;
        for (int k = 0; k < 16; ++k) {
            int col = t * 16 + k;
            int flag = (opcode[col] == 0) | (opcode[S_ + col] == 0);
            fl |= (unsigned)flag << k; c += flag;
        }
        cnts[t] = c;
        __syncthreads();
        for (int off = 1; off < 256; off <<= 1) {
            int v = cnts[t];
            int a = (t >= off) ? cnts[t - off] : 0;
            __syncthreads();
            cnts[t] = v + a;
            __syncthreads();
        }
        int base = cnts[t] - c;
        for (int k = 0; k < 16; ++k)
            if ((fl >> k) & 1) glist[base++] = t * 16 + k;
        int G = cnts[255];
        if (t == 255) gcount[0] = G;
        // pad tail with -1 so attention can load int4 unguarded
        for (int k = 0; k < 8; ++k) {
            int idx = G + t + k * 256;
            if (idx < S_) glist[idx] = -1;
        }
    }
}

// ---------------- fp16 GEMM core (128x128, BK=32, 4 waves, dbuf) ------------
// LDS per buffer (ushort idx): tile(A0/B1)*4096 + kg*1024 + row*8
__device__ __forceinline__ void gemm_core1(const ushort_t* __restrict__ A,
                                           const ushort_t* __restrict__ Bw,
                                           ushort_t (&LDS)[2][8192],
                                           int m0, int n0, int t,
                                           f32x4 (&acc)[4][4]) {
    const int lane = t & 63, wave = t >> 6;
    const int lrow = lane & 15, lkg = lane >> 4;
    const int wr = wave >> 1, wc = wave & 1;
    const ushort_t* srcs[2] = {A, Bw};
    const int row0[2] = {m0, n0};

    auto stage = [&](int buf, int k0) {
        #pragma unroll
        for (int it = 0; it < 4; ++it) {
            int c = it * 4 + wave;
            int tile = c >> 3;
            int kg = (c >> 1) & 3;
            int r = ((c & 1) << 6) | lane;
            const ushort_t* g = srcs[tile] + (size_t)(row0[tile] + r) * 512 + k0 + kg * 8;
            __builtin_amdgcn_global_load_lds(
                (const __attribute__((address_space(1))) void*)g,
                (__attribute__((address_space(3))) void*)(&LDS[buf][c * 512]),
                16, 0, 0);
        }
    };

    stage(0, 0);
    __syncthreads();

    const int aoff = lkg * 1024 + (wr * 64 + lrow) * 8;
    const int boff = 4096 + lkg * 1024 + (wc * 64 + lrow) * 8;
    int cur = 0;
    for (int ks = 0; ks < 16; ++ks) {
        if (ks < 15) stage(cur ^ 1, (ks + 1) * 32);
        const ushort_t* Lb = LDS[cur];
        half8 ah[4], bh[4];
        #pragma unroll
        for (int m = 0; m < 4; ++m) ah[m] = *(const half8*)(Lb + aoff + m * 128);
        #pragma unroll
        for (int n = 0; n < 4; ++n) bh[n] = *(const half8*)(Lb + boff + n * 128);
        #pragma unroll
        for (int m = 0; m < 4; ++m)
            #pragma unroll
            for (int n = 0; n < 4; ++n)
                acc[m][n] = __builtin_amdgcn_mfma_f32_16x16x32_f16(ah[m], bh[n], acc[m][n], 0, 0, 0);
        __syncthreads();
        cur ^= 1;
    }
}

// merged Q/K/V projection: z=0 Q (swapped), z=1 K (swapped), z=2 V (normal)
__global__ __launch_bounds__(256) void gemm_qkv(const ushort_t* __restrict__ xh,
                                                const ushort_t* __restrict__ whb,
                                                const float* __restrict__ bq,
                                                const float* __restrict__ bk,
                                                const float* __restrict__ bv,
                                                ushort_t* __restrict__ qb,
                                                char* __restrict__ bandimg) {
    __shared__ ushort_t LDS[2][8192];
    const int z = blockIdx.z;
    const int t = threadIdx.x;
    const ushort_t* Wz = whb + (size_t)z * D_ * D_;
    const int lane = t & 63, wave = t >> 6;
    const int lrow = lane & 15, lkg = lane >> 4;
    const int wr = wave >> 1, wc = wave & 1;

    f32x4 acc[4][4];
    for (int m = 0; m < 4; ++m)
        for (int n = 0; n < 4; ++n)
            acc[m][n] = f32x4{0.f, 0.f, 0.f, 0.f};

    if (z == 2) {
        // V: A = x rows (s), B = Wv rows (d)
        const int m0 = blockIdx.y * 128, n0 = blockIdx.x * 128;
        gemm_core1(xh, Wz, LDS, m0, n0, t, acc);
        for (int m = 0; m < 4; ++m) {
            int s_base = m0 + wr * 64 + m * 16 + lkg * 4;
            int bb = s_base >> 12, s0 = s_base & (S_ - 1);
            int jt = s0 >> 6, jr0 = s0 & 63;
            for (int n = 0; n < 4; ++n) {
                int col = n0 + wc * 64 + n * 16 + lrow;
                float bs = bv[col];
                int hh = col >> 6, dk = col & 63;
                us4 pk;
                for (int r = 0; r < 4; ++r) pk[r] = f2h(acc[m][n][r] + bs);
                char* img = bandimg + (((size_t)(bb * H_ + hh)) * 64 + jt) * 16384 + 8192;
                *(us4*)(img + ((dk * 128 + jr0 * 2) ^ ((dk & 7) << 4))) = pk;
            }
        }
    } else {
        // Q/K swapped: A = W rows (d), B = x rows (s)
        const int m0 = blockIdx.x * 128, n0 = blockIdx.y * 128;
        gemm_core1(Wz, xh, LDS, m0, n0, t, acc);
        const float* bias = (z == 0) ? bq : bk;
        for (int m = 0; m < 4; ++m) {
            int d_base = m0 + wr * 64 + m * 16 + lkg * 4;
            f32x4 b4 = *(const f32x4*)(bias + d_base);
            int hh = d_base >> 6, dkb = d_base & 63;
            for (int n = 0; n < 4; ++n) {
                int s = n0 + wc * 64 + n * 16 + lrow;
                int bb = s >> 12, sl = s & (S_ - 1);
                us4 pk;
                if (z == 0) {
                    for (int r = 0; r < 4; ++r) pk[r] = f2h((acc[m][n][r] + b4[r]) * QSCALE);
                    *(us4*)(qb + (((size_t)(bb * H_ + hh) * S_) + sl) * DK_ + dkb) = pk;
                } else {
                    for (int r = 0; r < 4; ++r) pk[r] = f2h(acc[m][n][r] + b4[r]);
                    int jt = sl >> 6, jr = sl & 63;
                    char* img = bandimg + (((size_t)(bb * H_ + hh)) * 64 + jt) * 16384;
                    *(us4*)(img + ((jr * 128 + dkb * 2) ^ ((jr & 7) << 4))) = pk;
                }
            }
        }
    }
}

// final projection (swapped, pure fp16): 64(d)x128(s) tiles, 512 blocks
// LDS per buffer: A(Wo) 64x32 at [0..2047], B(ao) 128x32 at [2048..6143]
__global__ __launch_bounds__(256) void gemm_fin(const ushort_t* __restrict__ Woh,
                                                const ushort_t* __restrict__ aoh,
                                                const float* __restrict__ bias,
                                                float* __restrict__ outp) {
    __shared__ ushort_t LDS[2][6144];
    const int t = threadIdx.x;
    const int lane = t & 63, wave = t >> 6;
    const int lrow = lane & 15, lkg = lane >> 4;
    const int wr = wave >> 1, wc = wave & 1;
    const int m0 = blockIdx.x * 64, n0 = blockIdx.y * 128;

    auto stage = [&](int buf, int k0) {
        #pragma unroll
        for (int it = 0; it < 3; ++it) {
            int c = it * 4 + wave;
            const ushort_t* g;
            if (c < 4) {
                g = Woh + (size_t)(m0 + lane) * 512 + k0 + c * 8;       // kg = c
            } else {
                int s2 = c - 4;
                int kg = s2 >> 1, rh = s2 & 1;
                g = aoh + (size_t)(n0 + rh * 64 + lane) * 512 + k0 + kg * 8;
            }
            __builtin_amdgcn_global_load_lds(
                (const __attribute__((address_space(1))) void*)g,
                (__attribute__((address_space(3))) void*)(&LDS[buf][c * 512]),
                16, 0, 0);
        }
    };

    f32x4 acc[2][4];
    for (int m = 0; m < 2; ++m)
        for (int n = 0; n < 4; ++n)
            acc[m][n] = f32x4{0.f, 0.f, 0.f, 0.f};

    stage(0, 0);
    __syncthreads();

    const int aoff = lkg * 512 + (wr * 32 + lrow) * 8;
    const int boff = 2048 + lkg * 1024 + (wc * 64 + lrow) * 8;
    int cur = 0;
    for (int ks = 0; ks < 16; ++ks) {
        if (ks < 15) stage(cur ^ 1, (ks + 1) * 32);
        const ushort_t* Lb = LDS[cur];
        half8 ah[2], bh[4];
        #pragma unroll
        for (int m = 0; m < 2; ++m) ah[m] = *(const half8*)(Lb + aoff + m * 128);
        #pragma unroll
        for (int n = 0; n < 4; ++n) bh[n] = *(const half8*)(Lb + boff + n * 128);
        #pragma unroll
        for (int m = 0; m < 2; ++m)
            #pragma unroll
            for (int n = 0; n < 4; ++n)
                acc[m][n] = __builtin_amdgcn_mfma_f32_16x16x32_f16(ah[m], bh[n], acc[m][n], 0, 0, 0);
        __syncthreads();
        cur ^= 1;
    }

    for (int m = 0; m < 2; ++m) {
        int d_base = m0 + wr * 32 + m * 16 + lkg * 4;
        f32x4 b4 = *(const f32x4*)(bias + d_base);
        for (int n = 0; n < 4; ++n) {
            int s = n0 + wc * 64 + n * 16 + lrow;
            f32x4 o;
            for (int r = 0; r < 4; ++r) o[r] = acc[m][n][r] + b4[r];
            *(f32x4*)(outp + (size_t)s * D_ + d_base) = o;
        }
    }
}

// ---------------- gather global-column chunks into images -------------------
__global__ __launch_bounds__(256) void prep_glob(const char* __restrict__ bandimg,
                                                 char* __restrict__ globimg,
                                                 const int* __restrict__ glist,
                                                 const int* __restrict__ gcount) {
    int G = gcount[0];
    int gc = blockIdx.x;
    if (gc * 64 >= G) return;
    int h = blockIdx.y, b = blockIdx.z;
    int t = threadIdx.x;
    __shared__ int jl[64];
    if (t < 64) { int gi = gc * 64 + t; jl[t] = (gi < G) ? glist[gi] : -1; }
    __syncthreads();
    const size_t bh = (size_t)(b * H_ + h);
    char* dst = globimg + (bh * NGT + gc) * 16384;
    {
        int c = t >> 2, q = t & 3;
        int jj = jl[c];
        #pragma unroll
        for (int p = 0; p < 2; ++p) {
            int o_dst = c * 128 + q * 32 + p * 16;
            __attribute__((ext_vector_type(8))) short val;
            if (jj >= 0) {
                int jr = jj & 63, jt = jj >> 6;
                const char* src = bandimg + (bh * 64 + jt) * 16384;
                val = *(const __attribute__((ext_vector_type(8))) short*)
                      (src + ((jr * 128 + q * 32 + p * 16) ^ ((jr & 7) << 4)));
            } else {
                for (int e = 0; e < 8; ++e) val[e] = 0;
            }
            *(__attribute__((ext_vector_type(8))) short*)(dst + (o_dst ^ ((c & 7) << 4))) = val;
        }
    }
    {
        int d = t >> 2, qq = t & 3;
        __attribute__((ext_vector_type(8))) short v0, v1;
        #pragma unroll 16
        for (int i = 0; i < 16; ++i) {
            int c = qq * 16 + i;
            int jj = jl[c];
            ushort_t val = 0;
            if (jj >= 0) {
                int jr = jj & 63, jt = jj >> 6;
                const char* src = bandimg + (bh * 64 + jt) * 16384 + 8192;
                val = *(const ushort_t*)(src + ((d * 128 + jr * 2) ^ ((d & 7) << 4)));
            }
            if (i < 8) v0[i] = val; else v1[i - 8] = val;
        }
        int o = d * 128 + qq * 32;
        *(__attribute__((ext_vector_type(8))) short*)(dst + 8192 + (o ^ ((d & 7) << 4))) = v0;
        *(__attribute__((ext_vector_type(8))) short*)(dst + 8192 + ((o + 16) ^ ((d & 7) << 4))) = v1;
    }
}

// ---------------- sparse flash attention: fp16, needmask, setprio -----------
// grid: 1-D 512 blocks; bh = bid & 15 keeps each (b,h)'s images XCD-local.
__global__ __launch_bounds__(512) void attn_mfma6(const ushort_t* __restrict__ Qp,
                                                  const char* __restrict__ bandimg,
                                                  const char* __restrict__ globimg,
                                                  const int* __restrict__ glist,
                                                  const int* __restrict__ gcount,
                                                  ushort_t* __restrict__ AO) {
    __shared__ char buf[2][16384];           // [K 8KB][Vt 8KB]
    __shared__ ushort_t Ps[8 * 16 * 64];     // per-wave P^T, swizzled

    const int t = threadIdx.x, lane = t & 63, wave = t >> 6;
    const int q = lane & 15, g = lane >> 4;
    const int bid = blockIdx.x;
    const int bh_lin = bid & 15;              // XCD-local (b,h)
    const int b = bh_lin >> 3, h = bh_lin & 7;
    const int i0 = (bid >> 4) * 128;
    const size_t headoff = ((size_t)(b * H_ + h)) * S_ * DK_;
    const int iq = i0 + wave * 16 + q;
    const int iqm = iq - WIN_;

    half8 qa[2];
    {
        const ushort_t* qrow = Qp + headoff + (size_t)iq * DK_;
        qa[0] = *(const half8*)(qrow + 8 * g);
        qa[1] = *(const half8*)(qrow + 32 + 8 * g);
    }

    f32x4 Oa[4];
    for (int n = 0; n < 4; ++n) Oa[n] = f32x4{0.f, 0.f, 0.f, 0.f};
    float m_st = -1e30f, l_st = 0.f;

    int jlo = i0 - WIN_;
    int jt_lo = (jlo < 0) ? 0 : (jlo >> 6);
    int jhi = i0 + 127 + WIN_; if (jhi > S_ - 1) jhi = S_ - 1;
    int jt_hi = jhi >> 6;
    int nband = jt_hi - jt_lo + 1;
    const int G = gcount[0];
    int nglob = (G + 63) >> 6; if (nglob > NGT) nglob = NGT;
    int nchunk = nband + nglob;

    const size_t bh = (size_t)(b * H_ + h);

    // which glob chunks need the mask? (sorted glist -> range test; partial tail)
    unsigned needmask = 0;
    {
        int wmin = i0 - WIN_, wmax = i0 + 127 + WIN_;
        for (int gc = 0; gc < nglob; ++gc) {
            int lo = glist[gc * 64];
            int hidx = (gc * 64 + 63 < G) ? (gc * 64 + 63) : (G - 1);
            int hi = glist[hidx];
            bool nm = (lo <= wmax && hi >= wmin) || (gc == nglob - 1 && (G & 63));
            needmask |= (unsigned)nm << gc;
        }
    }

    // hoisted LDS offsets (chunk-invariant)
    int koff[4][2], poffw[4], poffr[2];
    #pragma unroll
    for (int n = 0; n < 4; ++n) {
        int row = n * 16 + q;
        #pragma unroll
        for (int kt = 0; kt < 2; ++kt)
            koff[n][kt] = (row * 128 + g * 16 + kt * 64) ^ ((row & 7) << 4);
        poffw[n] = (q * 128 + n * 32 + g * 8) ^ ((q & 7) << 4);
    }
    #pragma unroll
    for (int kt = 0; kt < 2; ++kt)
        poffr[kt] = (q * 128 + g * 16 + kt * 64) ^ ((q & 7) << 4);

    const char* band_base = bandimg + (bh * 64 + jt_lo) * 16384;
    const char* glob_base = globimg + (bh * NGT) * 16384;

    auto stage = [&](int ch, int nb) {
        const char* img = (ch < nband) ? (band_base + (size_t)ch * 16384)
                                       : (glob_base + (size_t)(ch - nband) * 16384);
        #pragma unroll
        for (int i = 0; i < 2; ++i) {
            int seg = wave * 2 + i;
            __builtin_amdgcn_global_load_lds(
                (const __attribute__((address_space(1))) void*)(img + seg * 1024 + lane * 16),
                (__attribute__((address_space(3))) void*)(buf[nb] + seg * 1024),
                16, 0, 0);
        }
    };

    stage(0, 0);
    __syncthreads();

    int cur = 0;
    for (int ch = 0; ch < nchunk; ++ch) {
        if (ch + 1 < nchunk) stage(ch + 1, cur ^ 1);
        const bool isband = ch < nband;
        const int cbase = isband ? (jt_lo + ch) * 64 : 0;
        const int gbase = (ch - nband) * 64;
        const char* Kb = buf[cur];
        const char* Vb = buf[cur] + 8192;

        // QK^T swapped: sc[n][r] = S[j = 16n+4g+r][q]  (log2 domain)
        f32x4 sc[4];
        for (int n = 0; n < 4; ++n) sc[n] = f32x4{0.f, 0.f, 0.f, 0.f};
        __builtin_amdgcn_s_setprio(1);
        #pragma unroll
        for (int n = 0; n < 4; ++n)
            #pragma unroll
            for (int kt = 0; kt < 2; ++kt) {
                half8 ka = *(const half8*)(Kb + koff[n][kt]);
                sc[n] = __builtin_amdgcn_mfma_f32_16x16x32_f16(ka, qa[kt], sc[n], 0, 0, 0);
            }
        __builtin_amdgcn_s_setprio(0);

        // mask (only where needed) + lane-local max
        float pm;
        bool nm = isband || ((needmask >> (ch - nband)) & 1);
        if (nm) {
            pm = -1e30f;
            if (isband) {
                #pragma unroll
                for (int n = 0; n < 4; ++n) {
                    int jb = cbase + n * 16 + 4 * g;
                    #pragma unroll
                    for (int r = 0; r < 4; ++r) {
                        bool inwin = (unsigned)(jb + r - iqm) <= 2 * WIN_;
                        float s = inwin ? sc[n][r] : -1e30f;
                        sc[n][r] = s;
                        pm = fmaxf(pm, s);
                    }
                }
            } else {
                #pragma unroll
                for (int n = 0; n < 4; ++n) {
                    int4 J = *(const int4*)(glist + gbase + n * 16 + g * 4);
                    int js[4] = {J.x, J.y, J.z, J.w};
                    #pragma unroll
                    for (int r = 0; r < 4; ++r) {
                        int jj = js[r];
                        bool inwin = (unsigned)(jj - iqm) <= 2 * WIN_;
                        bool allow = (jj >= 0) && !inwin;
                        float s = allow ? sc[n][r] : -1e30f;
                        sc[n][r] = s;
                        pm = fmaxf(pm, s);
                    }
                }
            }
        } else {
            float a0 = fmaxf(fmaxf(sc[0][0], sc[0][1]), fmaxf(sc[0][2], sc[0][3]));
            float a1 = fmaxf(fmaxf(sc[1][0], sc[1][1]), fmaxf(sc[1][2], sc[1][3]));
            float a2 = fmaxf(fmaxf(sc[2][0], sc[2][1]), fmaxf(sc[2][2], sc[2][3]));
            float a3 = fmaxf(fmaxf(sc[3][0], sc[3][1]), fmaxf(sc[3][2], sc[3][3]));
            pm = fmaxf(fmaxf(a0, a1), fmaxf(a2, a3));
        }
        pm = fmaxf(pm, __shfl_xor(pm, 16, 64));
        pm = fmaxf(pm, __shfl_xor(pm, 32, 64));

        bool skip = __all(pm <= m_st);   // exact: fac would be 1
        float fac = 1.0f;
        if (!skip) {
            float mn = fmaxf(m_st, pm);
            fac = v_exp2(m_st - mn);
            m_st = mn;
        }
        float rs = 0.f;
        #pragma unroll
        for (int n = 0; n < 4; ++n)
            #pragma unroll
            for (int r = 0; r < 4; ++r) {
                float p = v_exp2(sc[n][r] - m_st);
                sc[n][r] = p;
                rs += p;
            }
        rs += __shfl_xor(rs, 16, 64);
        rs += __shfl_xor(rs, 32, 64);
        l_st = skip ? (l_st + rs) : (l_st * fac + rs);

        // P^T -> wave-private LDS via v_cvt_pkrtz_f16_f32 (b64 writes)
        ushort_t* Pw = Ps + wave * 1024;
        #pragma unroll
        for (int n = 0; n < 4; ++n) {
            unsigned pk0 = cvt_pk_f16(sc[n][0], sc[n][1]);
            unsigned pk1 = cvt_pk_f16(sc[n][2], sc[n][3]);
            *(unsigned long long*)((char*)Pw + poffw[n]) =
                ((unsigned long long)pk1 << 32) | pk0;
        }

        if (!skip) {
            #pragma unroll
            for (int n = 0; n < 4; ++n)
                #pragma unroll
                for (int r = 0; r < 4; ++r) Oa[n][r] *= fac;
        }

        half8 pa[2];
        #pragma unroll
        for (int kt = 0; kt < 2; ++kt)
            pa[kt] = *(const half8*)((char*)Pw + poffr[kt]);
        __builtin_amdgcn_s_setprio(1);
        #pragma unroll
        for (int n = 0; n < 4; ++n)
            #pragma unroll
            for (int kt = 0; kt < 2; ++kt) {
                half8 va = *(const half8*)(Vb + koff[n][kt]);
                Oa[n] = __builtin_amdgcn_mfma_f32_16x16x32_f16(va, pa[kt], Oa[n], 0, 0, 0);
            }
        __builtin_amdgcn_s_setprio(0);
        __syncthreads();
        cur ^= 1;
    }

    // epilogue: normalize, write fp16 AO
    float inv = 1.0f / l_st;
    #pragma unroll
    for (int n = 0; n < 4; ++n) {
        us4 ph;
        #pragma unroll
        for (int r = 0; r < 4; ++r) ph[r] = f2h(Oa[n][r] * inv);
        size_t base = ((size_t)b * S_ + iq) * D_ + h * DK_ + (n * 16 + g * 4);
        *(us4*)(AO + base) = ph;
    }
}

// ---------------- launch ----------------------------------------------------
extern "C" void kernel_launch(void* const* d_in, const int* in_sizes, int n_in,
                              void* d_out, int out_size, void* d_ws, size_t ws_size,
                              hipStream_t stream) {
    const float* x      = (const float*)d_in[0];
    const int*   opcode = (const int*)d_in[1];
    const float* Wq = (const float*)d_in[2];
    const float* bq = (const float*)d_in[3];
    const float* Wk = (const float*)d_in[4];
    const float* bk = (const float*)d_in[5];
    const float* Wv = (const float*)d_in[6];
    const float* bv = (const float*)d_in[7];
    const float* Wo = (const float*)d_in[8];
    const float* bo = (const float*)d_in[9];
    float* out = (float*)d_out;

    char* ws = (char*)d_ws;
    const size_t bsd = (size_t)B_ * S_ * D_;
    const size_t hf_bytes = bsd * sizeof(ushort_t);                 // 8.39 MB
    const size_t w_bytes  = (size_t)D_ * D_ * sizeof(ushort_t);     // 0.52 MB

    ushort_t* qb = (ushort_t*)(ws);
    ushort_t* xh = (ushort_t*)(ws + hf_bytes);
    ushort_t* ao = xh;                          // reuse after projections
    char* wbase = ws + 2 * hf_bytes;
    ushort_t* whb = (ushort_t*)wbase;           // 4 weights fp16, contiguous
    char* bandimg = wbase + 4 * w_bytes;                         // 16*64*16KB
    char* globimg = bandimg + (size_t)16 * 64 * 16384;           // 16*NGT*16KB
    int* glist  = (int*)(globimg + (size_t)16 * NGT * 16384);
    int* gcount = glist + S_;

    prep_all<<<5121, 256, 0, stream>>>(x, Wq, Wk, Wv, Wo, opcode,
                                       xh, whb, glist, gcount);

    gemm_qkv<<<dim3(D_ / 128, (B_ * S_) / 128, 3), 256, 0, stream>>>(
        xh, whb, bq, bk, bv, qb, bandimg);

    prep_glob<<<dim3(NGT, H_, B_), 256, 0, stream>>>(bandimg, globimg, glist, gcount);

    attn_mfma6<<<dim3(512), 512, 0, stream>>>(
        qb, bandimg, globimg, glist, gcount, ao);

    gemm_fin<<<dim3(D_ / 64, (B_ * S_) / 128), 256, 0, stream>>>(
        whb + 3 * (size_t)D_ * D_, ao, bo, out);
}